// Round 2
// baseline (1045.499 us; speedup 1.0000x reference)
//
#include <hip/hip_runtime.h>

#define FIN 128
#define FHID 32
#define FOUT 64
#define MAXDEG 10
#define BSH 8              // dst bucket = dst >> 8 (256 dsts per bucket)
#define ACHUNK 4096        // edges per pass-A workgroup (16 per thread)
#define XPAD 136           // LDS row stride (bf16) for 128-k tiles
#define YPAD 40            // LDS row stride (bf16) for 32-k tiles: 80B, 16B-aligned
#define HPAD 33            // LDS f32 accumulator row stride: (r*33+f)%32 spreads banks

typedef __attribute__((ext_vector_type(8))) short short8;
typedef __attribute__((ext_vector_type(4))) float f32x4;

// edge_index arrives as int32: layout [2, E] flat: src = ei[e], dst = ei[E + e].

__device__ __forceinline__ float bf2f(unsigned short u) {
    union { unsigned int i; float f; } c; c.i = ((unsigned int)u) << 16; return c.f;
}
__device__ __forceinline__ unsigned short f2bf(float f) {
    union { float f; unsigned int i; } c; c.f = f;
    unsigned int r = c.i + 0x7FFF + ((c.i >> 16) & 1);   // round-nearest-even
    return (unsigned short)(r >> 16);
}
__device__ __forceinline__ float bflo(unsigned int w) { return bf2f((unsigned short)(w & 0xffff)); }
__device__ __forceinline__ float bfhi(unsigned int w) { return bf2f((unsigned short)(w >> 16)); }
__device__ __forceinline__ unsigned int pk2(float lo, float hi) {
    return (unsigned int)f2bf(lo) | ((unsigned int)f2bf(hi) << 16);
}

// ---------- CSR build ----------

__global__ __launch_bounds__(256) void k_count(const int* __restrict__ ei, int E, int N,
                                               int* __restrict__ deg) {
    int e = blockIdx.x * 256 + threadIdx.x;
    if (e >= E) return;
    int d = ei[E + e];
    if ((unsigned)d < (unsigned)N) atomicAdd(deg + d, 1);
}

__global__ __launch_bounds__(256) void k_blocksum(const int* __restrict__ deg, int N,
                                                  int* __restrict__ partial) {
    __shared__ int tmp[256];
    int t = threadIdx.x;
    int i = blockIdx.x * 256 + t;
    tmp[t] = (i < N) ? deg[i] : 0;
    __syncthreads();
    for (int off = 128; off > 0; off >>= 1) {
        if (t < off) tmp[t] += tmp[t + off];
        __syncthreads();
    }
    if (t == 0) partial[blockIdx.x] = tmp[0];
}

// single-block exclusive scan of partial[0..NB) -> offsets   (requires NB <= 1024)
__global__ __launch_bounds__(1024) void k_scanpartial(const int* __restrict__ partial, int NB,
                                                      int* __restrict__ offsets) {
    __shared__ int tmp[1024];
    int t = threadIdx.x;
    int v = (t < NB) ? partial[t] : 0;
    tmp[t] = v;
    __syncthreads();
    for (int off = 1; off < 1024; off <<= 1) {
        int a = (t >= off) ? tmp[t - off] : 0;
        __syncthreads();
        tmp[t] += a;
        __syncthreads();
    }
    if (t < NB) offsets[t] = tmp[t] - v;
}

__global__ __launch_bounds__(256) void k_scandeg(const int* __restrict__ deg, int N,
                                                 const int* __restrict__ offsets,
                                                 int* __restrict__ cursor) {
    __shared__ int tmp[256];
    int t = threadIdx.x;
    int i = blockIdx.x * 256 + t;
    int v = (i < N) ? deg[i] : 0;
    tmp[t] = v;
    __syncthreads();
    for (int off = 1; off < 256; off <<= 1) {
        int a = (t >= off) ? tmp[t - off] : 0;
        __syncthreads();
        tmp[t] += a;
        __syncthreads();
    }
    if (i < N) cursor[i] = offsets[blockIdx.x] + tmp[t] - v;
}

// gcur[b] = bstart[b] = adj/pairs start offset of bucket b
__global__ __launch_bounds__(256) void k_initb(const int* __restrict__ cursor,
                                               int* __restrict__ gcur,
                                               int* __restrict__ bstart, int K) {
    int b = blockIdx.x * 256 + threadIdx.x;
    if (b < K) { int v = cursor[b << BSH]; gcur[b] = v; bstart[b] = v; }
}

// Pass A: bucket edges by dst>>8 into pairs[], line-coalesced appends.
__global__ __launch_bounds__(256) void k_passA(const int* __restrict__ ei, int E, int N,
                                               int* __restrict__ gcur,
                                               int2* __restrict__ pairs) {
    __shared__ int hist[1024];
    __shared__ int base[1024];
    int K = ((N + 255) >> BSH);
    int t = threadIdx.x;
    long long cb = (long long)blockIdx.x * ACHUNK;
    for (int i = t; i < K; i += 256) hist[i] = 0;
    __syncthreads();
    int sv[16], dv[16];
#pragma unroll
    for (int i = 0; i < 16; ++i) {
        sv[i] = -1; dv[i] = 0;
        long long e = cb + t + (long long)i * 256;
        if (e < E) {
            int ss = ei[e];
            int dd = ei[E + e];
            if ((unsigned)ss < (unsigned)N && (unsigned)dd < (unsigned)N) {
                sv[i] = ss; dv[i] = dd;
            }
        }
    }
#pragma unroll
    for (int i = 0; i < 16; ++i)
        if (sv[i] >= 0) atomicAdd(&hist[dv[i] >> BSH], 1);
    __syncthreads();
    for (int i = t; i < K; i += 256) {
        int h = hist[i];
        base[i] = h ? atomicAdd(&gcur[i], h) : 0;
    }
    __syncthreads();
    for (int i = t; i < K; i += 256) hist[i] = 0;
    __syncthreads();
#pragma unroll
    for (int i = 0; i < 16; ++i) {
        if (sv[i] >= 0) {
            int b = dv[i] >> BSH;
            int off = atomicAdd(&hist[b], 1);
            pairs[base[b] + off] = make_int2(sv[i], dv[i]);
        }
    }
}

// Pass B (flagged-only): build adj rows only for deg<MAXDEG dsts (k_fix1 consumers).
__global__ __launch_bounds__(256) void k_passB(const int2* __restrict__ pairs,
                                               const int* __restrict__ gcur,
                                               const int* __restrict__ bstart,
                                               const int* __restrict__ deg,
                                               int* __restrict__ cursor,
                                               int* __restrict__ adj, int N) {
    __shared__ int cur[256];
    __shared__ unsigned char fl[256];
    int b = blockIdx.x;
    int lo = b << BSH;
    int hi = min(lo + 256, N);
    int t = threadIdx.x;
    int cnt = hi - lo;
    if (t < cnt) { cur[t] = cursor[lo + t]; fl[t] = (deg[lo + t] < MAXDEG); }
    int pstart = bstart[b];
    int pend = gcur[b];
    __syncthreads();
    for (int i = pstart + t; i < pend; i += 256) {
        int2 pr = pairs[i];
        int r = pr.y - lo;
        if (fl[r]) {
            int pos = atomicAdd(&cur[r], 1);
            adj[pos] = pr.x;
        }
    }
    __syncthreads();
    if (t < cnt && fl[t]) cursor[lo + t] = cur[t];   // row end, consumed by k_fix1
}

// ---------- prepack bucket-10 weights as bf16, B-operand layout [n][k] ----------
__global__ __launch_bounds__(256) void k_prepack(const float* __restrict__ W1,
                                                 const float* __restrict__ Wr1,
                                                 const float* __restrict__ W2,
                                                 const float* __restrict__ Wr2,
                                                 unsigned short* __restrict__ wcat1,
                                                 unsigned short* __restrict__ wcat2w,
                                                 unsigned short* __restrict__ wcat2r) {
    int t = threadIdx.x;
    const float* W1b  = W1  + (size_t)MAXDEG * FIN * FHID;
    const float* Wr1b = Wr1 + (size_t)MAXDEG * FIN * FHID;
    const float* W2b  = W2  + (size_t)MAXDEG * FHID * FOUT;
    const float* Wr2b = Wr2 + (size_t)MAXDEG * FHID * FOUT;
    for (int i = 0; i < 32; ++i) {
        int idx = i * 256 + t;            // 8192
        int n = idx >> 7, k = idx & 127;
        float v = (n < 32) ? W1b[k * FHID + n] : Wr1b[k * FHID + (n - 32)];
        wcat1[idx] = f2bf(v);
    }
    for (int i = 0; i < 8; ++i) {
        int idx = i * 256 + t;            // 2048 each: [64 n][32 k]
        int n = idx >> 5, k = idx & 31;
        wcat2w[idx] = f2bf(W2b[k * FOUT + n]);
        wcat2r[idx] = f2bf(Wr2b[k * FOUT + n]);
    }
}

// ---------- pre1 (MFMA): [z10 | r1] = x @ [W1[10] | Wr1[10]] + [0 | b1[10]] ----------
__global__ __launch_bounds__(256) void k_pre1m(const float* __restrict__ x,
                                               const unsigned short* __restrict__ wcat1,
                                               const float* __restrict__ b1,
                                               unsigned short* __restrict__ z10,
                                               unsigned short* __restrict__ r1, int N) {
    __shared__ __align__(16) unsigned short xt[64 * XPAD];
    __shared__ __align__(16) unsigned short wt[64 * XPAD];
    int t = threadIdx.x;
    int row0 = blockIdx.x * 64;
    {   // stage Wcat1 (8192 bf16 = 1024 uint4)
        const uint4* src = (const uint4*)wcat1;
#pragma unroll
        for (int i = 0; i < 4; ++i) {
            int idx = i * 256 + t;
            uint4 v = src[idx];
            int n = idx >> 4;
            int k = (idx & 15) * 8;
            *(uint4*)(wt + n * XPAD + k) = v;
        }
    }
    {   // stage x rows -> bf16
        int r = t >> 2;
        int c0 = (t & 3) * 32;
        int cr = min(row0 + r, N - 1);
        const float4* xs = (const float4*)(x + (size_t)cr * FIN + c0);
        unsigned short* dst = xt + r * XPAD + c0;
#pragma unroll
        for (int i = 0; i < 8; ++i) {
            float4 v = xs[i];
            ushort4 b;
            b.x = f2bf(v.x); b.y = f2bf(v.y); b.z = f2bf(v.z); b.w = f2bf(v.w);
            *(ushort4*)(dst + i * 4) = b;
        }
    }
    __syncthreads();
    int w = t >> 6, lane = t & 63;
    int m = lane & 15, quad = lane >> 4;
    const unsigned short* arow = xt + (w * 16 + m) * XPAD + quad * 8;
    short8 af[4];
#pragma unroll
    for (int kt = 0; kt < 4; ++kt) af[kt] = *(const short8*)(arow + kt * 32);
    f32x4 acc[4];
#pragma unroll
    for (int ct = 0; ct < 4; ++ct) acc[ct] = (f32x4){0.f, 0.f, 0.f, 0.f};
#pragma unroll
    for (int ct = 0; ct < 4; ++ct) {
        const unsigned short* brow = wt + (ct * 16 + m) * XPAD + quad * 8;
#pragma unroll
        for (int kt = 0; kt < 4; ++kt) {
            short8 bfr = *(const short8*)(brow + kt * 32);
            acc[ct] = __builtin_amdgcn_mfma_f32_16x16x32_bf16(af[kt], bfr, acc[ct], 0, 0, 0);
        }
    }
    int rbase = row0 + w * 16 + quad * 4;
#pragma unroll
    for (int ct = 0; ct < 4; ++ct) {
        float bias = (ct >= 2) ? b1[MAXDEG * FHID + (ct - 2) * 16 + m] : 0.f;
#pragma unroll
        for (int rg = 0; rg < 4; ++rg) {
            int n = rbase + rg;
            if (n < N) {
                float v = acc[ct][rg];
                if (ct < 2) z10[(size_t)n * FHID + ct * 16 + m] = f2bf(v);
                else        r1[(size_t)n * FHID + (ct - 2) * 16 + m] = f2bf(v + bias);
            }
        }
    }
}

// fixup+slow path for deg<10 nodes: full layer1 output via true-bucket weights.
__global__ __launch_bounds__(256) void k_fix1(const float* __restrict__ x,
                                              const int* __restrict__ deg,
                                              const int* __restrict__ cursor,
                                              const int* __restrict__ adj,
                                              const float* __restrict__ W1,
                                              const float* __restrict__ b1,
                                              const float* __restrict__ Wr1,
                                              unsigned short* __restrict__ out1, int N) {
    int wavebase = blockIdx.x * 256 + (threadIdx.x & 192);
    int lane = threadIdx.x & 63;
    int nl = wavebase + lane;
    bool fl = (nl < N) && (deg[nl] < MAXDEG);
    unsigned long long mask = __ballot(fl);
    int u = lane >> 5, o = lane & 31;
    while (mask) {
        int b = __ffsll(mask) - 1;
        mask &= mask - 1;
        int n = wavebase + b;
        int d = deg[n];
        // root term: Wr1[d]^T x_n  (split-K across halves u)
        const float* Wr = Wr1 + (size_t)d * (FIN * FHID) + o;
        const float4* xr = (const float4*)(x + (size_t)n * FIN);
        float racc = 0.f;
        for (int c = u * 16; c < u * 16 + 16; ++c) {
            float4 xv = xr[c];
            racc += xv.x * Wr[(c * 4 + 0) * FHID] + xv.y * Wr[(c * 4 + 1) * FHID]
                  + xv.z * Wr[(c * 4 + 2) * FHID] + xv.w * Wr[(c * 4 + 3) * FHID];
        }
        racc += __shfl_xor(racc, 32);
        // neighbor aggregate: h = sum x_j  (feats lane*2, lane*2+1 per lane)
        int e1 = cursor[n];
        int e0 = e1 - d;
        float2 h = make_float2(0.f, 0.f);
        for (int k = e0; k < e1; ++k) {
            int s = adj[k];
            float2 v = *(const float2*)(x + (size_t)s * FIN + lane * 2);
            h.x += v.x; h.y += v.y;
        }
        // transform: W1[d]^T h  (split-K across halves u)
        const float* Wp = W1 + (size_t)d * (FIN * FHID) + o;
        float acc = 0.f;
        for (int f = u * 64; f < u * 64 + 64; ++f) {
            float hf = __shfl((f & 1) ? h.y : h.x, f >> 1);
            acc += hf * Wp[f * FHID];
        }
        acc += __shfl_xor(acc, 32);
        if (lane < 32) {
            float rv = racc + b1[d * FHID + o];
            out1[(size_t)n * FHID + o] = f2bf(fmaxf(acc + rv, 0.f));
        }
    }
}

// ---------- edge-parallel LDS aggregation (shared by both layers) ----------
// 4 lanes per edge, uint4 (8 feats) per lane, 4-deep unroll (8 loads in flight/wave).
__device__ __forceinline__ void agg8(float* hp, uint4 v, float sc) {
    atomicAdd(hp + 0, sc * bflo(v.x)); atomicAdd(hp + 1, sc * bfhi(v.x));
    atomicAdd(hp + 2, sc * bflo(v.y)); atomicAdd(hp + 3, sc * bfhi(v.y));
    atomicAdd(hp + 4, sc * bflo(v.z)); atomicAdd(hp + 5, sc * bfhi(v.z));
    atomicAdd(hp + 6, sc * bflo(v.w)); atomicAdd(hp + 7, sc * bfhi(v.w));
}

__device__ __forceinline__ void aggregate_bucket(const int2* __restrict__ pairs,
                                                 const unsigned short* __restrict__ rows,
                                                 float* h, int p0, int p1, int lo, int t) {
    if (p1 <= p0) return;
    int pe = p1 - 1;
    int s = t & 3;                      // quarter-row (8 feats = 16B)
    for (int k0 = p0 + (t >> 2); k0 < p1; k0 += 512) {
        int kb = k0 + 128, kc = k0 + 256, kd = k0 + 384;
        int2 ea = pairs[k0];
        int2 eb = pairs[min(kb, pe)];
        int2 ec = pairs[min(kc, pe)];
        int2 ed = pairs[min(kd, pe)];
        uint4 va = *(const uint4*)(rows + (size_t)ea.x * FHID + s * 8);
        uint4 vb = *(const uint4*)(rows + (size_t)eb.x * FHID + s * 8);
        uint4 vc = *(const uint4*)(rows + (size_t)ec.x * FHID + s * 8);
        uint4 vd = *(const uint4*)(rows + (size_t)ed.x * FHID + s * 8);
        agg8(h + (ea.y - lo) * HPAD + s * 8, va, 1.f);
        agg8(h + (eb.y - lo) * HPAD + s * 8, vb, (kb < p1) ? 1.f : 0.f);
        agg8(h + (ec.y - lo) * HPAD + s * 8, vc, (kc < p1) ? 1.f : 0.f);
        agg8(h + (ed.y - lo) * HPAD + s * 8, vd, (kd < p1) ? 1.f : 0.f);
    }
}

// ---------- layer1: per-bucket aggregate z10 -> out1 = relu(h + r1)  (deg>=10) ----------
__global__ __launch_bounds__(512) void k_layer1agg(const unsigned short* __restrict__ z10,
                                                   const unsigned short* __restrict__ r1,
                                                   const int* __restrict__ deg,
                                                   const int* __restrict__ bstart,
                                                   const int* __restrict__ gcur,
                                                   const int2* __restrict__ pairs,
                                                   unsigned short* __restrict__ out1, int N) {
    __shared__ float h[256 * HPAD];
    int b = blockIdx.x;
    int lo = b << BSH;
    int t = threadIdx.x;
    int cnt = min(256, N - lo);
    for (int i = t; i < 256 * HPAD; i += 512) h[i] = 0.f;
    __syncthreads();
    aggregate_bucket(pairs, z10, h, bstart[b], gcur[b], lo, t);
    __syncthreads();
    if (t < cnt && deg[lo + t] >= MAXDEG) {
        int n = lo + t;
        const float* hp = h + t * HPAD;
        const uint4* rp = (const uint4*)(r1 + (size_t)n * FHID);
        uint4 w[4];
#pragma unroll
        for (int i = 0; i < 4; ++i) {
            uint4 rv = rp[i];
            const float* hq = hp + i * 8;
            w[i].x = pk2(fmaxf(hq[0] + bflo(rv.x), 0.f), fmaxf(hq[1] + bfhi(rv.x), 0.f));
            w[i].y = pk2(fmaxf(hq[2] + bflo(rv.y), 0.f), fmaxf(hq[3] + bfhi(rv.y), 0.f));
            w[i].z = pk2(fmaxf(hq[4] + bflo(rv.z), 0.f), fmaxf(hq[5] + bfhi(rv.z), 0.f));
            w[i].w = pk2(fmaxf(hq[6] + bflo(rv.w), 0.f), fmaxf(hq[7] + bfhi(rv.w), 0.f));
        }
        uint4* op = (uint4*)(out1 + (size_t)n * FHID);
        op[0] = w[0]; op[1] = w[1]; op[2] = w[2]; op[3] = w[3];
    }
}

// ---------- layer2: per-bucket aggregate y -> MFMA epilogue, fused root term ----------
// out = g @ W2[10] + y @ Wr2[10] + b2[10] for deg>=10; exact VALU path for deg<10.
__global__ __launch_bounds__(512) void k_layer2agg(const unsigned short* __restrict__ y,
                                                   const int* __restrict__ deg,
                                                   const int* __restrict__ bstart,
                                                   const int* __restrict__ gcur,
                                                   const int2* __restrict__ pairs,
                                                   const unsigned short* __restrict__ w2w,
                                                   const unsigned short* __restrict__ w2r,
                                                   const float* __restrict__ W2full,
                                                   const float* __restrict__ Wr2full,
                                                   const float* __restrict__ b2,
                                                   float* __restrict__ out, int N) {
    __shared__ float g[256 * HPAD];                      // 33792 B
    __shared__ __align__(16) unsigned short yl[256 * YPAD]; // 20480 B (own rows, padded)
    __shared__ int flg[256];
    int b = blockIdx.x;
    int lo = b << BSH;
    int t = threadIdx.x;
    int cnt = min(256, N - lo);
    for (int i = t; i < 256 * HPAD; i += 512) g[i] = 0.f;
    if (t < 256) flg[t] = (t < cnt) ? (deg[lo + t] < MAXDEG) : 1;
    {   // stage own y rows: 256 rows x 64B; thread -> 32B
        int r = t >> 1, half = t & 1;
        int rn = min(lo + r, N - 1);
        const uint4* src = (const uint4*)(y + (size_t)rn * FHID + half * 16);
        uint4 v0 = src[0];
        uint4 v1 = src[1];
        uint4* dst = (uint4*)(yl + r * YPAD + half * 16);
        dst[0] = v0; dst[1] = v1;
    }
    __syncthreads();
    aggregate_bucket(pairs, y, g, bstart[b], gcur[b], lo, t);
    __syncthreads();

    int w = t >> 6, lane = t & 63;
    int m = lane & 15, quad = lane >> 4;
    {   // MFMA epilogue: wave w covers rows w*32 .. w*32+31 (2 m-tiles x 4 n-tiles)
        short8 bw[4], br[4];
#pragma unroll
        for (int ct = 0; ct < 4; ++ct) {
            bw[ct] = *(const short8*)(w2w + (ct * 16 + m) * FHID + quad * 8);
            br[ct] = *(const short8*)(w2r + (ct * 16 + m) * FHID + quad * 8);
        }
        f32x4 acc[2][4];
#pragma unroll
        for (int mt = 0; mt < 2; ++mt)
#pragma unroll
            for (int ct = 0; ct < 4; ++ct) acc[mt][ct] = (f32x4){0.f, 0.f, 0.f, 0.f};
#pragma unroll
        for (int mt = 0; mt < 2; ++mt) {
            int row = w * 32 + mt * 16 + m;
            short8 ay = *(const short8*)(yl + row * YPAD + quad * 8);
            short8 ag;
            const float* gp = g + row * HPAD + quad * 8;
#pragma unroll
            for (int j = 0; j < 8; ++j) ag[j] = (short)f2bf(gp[j]);
#pragma unroll
            for (int ct = 0; ct < 4; ++ct) {
                acc[mt][ct] = __builtin_amdgcn_mfma_f32_16x16x32_bf16(ay, br[ct], acc[mt][ct], 0, 0, 0);
                acc[mt][ct] = __builtin_amdgcn_mfma_f32_16x16x32_bf16(ag, bw[ct], acc[mt][ct], 0, 0, 0);
            }
        }
#pragma unroll
        for (int ct = 0; ct < 4; ++ct) {
            int o = ct * 16 + m;
            float bias = b2[MAXDEG * FOUT + o];
#pragma unroll
            for (int mt = 0; mt < 2; ++mt) {
#pragma unroll
                for (int rg = 0; rg < 4; ++rg) {
                    int r = w * 32 + mt * 16 + quad * 4 + rg;
                    if (r < cnt && !flg[r])
                        out[(size_t)(lo + r) * FOUT + o] = acc[mt][ct][rg] + bias;
                }
            }
        }
    }
    // exact path for flagged (deg<10) rows, distributed across the 8 waves
    int fidx = 0;
    for (int r = 0; r < cnt; ++r) {
        if (!flg[r]) continue;
        if ((fidx++ & 7) != w) continue;
        int n = lo + r;
        int d = deg[n];
        float acc2 = b2[d * FOUT + lane];
        const float* W2p  = W2full  + (size_t)d * (FHID * FOUT) + lane;
        const float* Wr2p = Wr2full + (size_t)d * (FHID * FOUT) + lane;
        const float* gp = g + r * HPAD;
        const unsigned short* yp = yl + r * YPAD;
#pragma unroll
        for (int f = 0; f < FHID; ++f) {
            acc2 += gp[f] * W2p[f * FOUT] + bf2f(yp[f]) * Wr2p[f * FOUT];
        }
        out[(size_t)n * FOUT + lane] = acc2;
    }
}

extern "C" void kernel_launch(void* const* d_in, const int* in_sizes, int n_in,
                              void* d_out, int out_size, void* d_ws, size_t ws_size,
                              hipStream_t stream) {
    const float* x   = (const float*)d_in[0];
    const int*   ei  = (const int*)d_in[1];   // int32, [2, E] flat
    const float* W1  = (const float*)d_in[2];
    const float* b1  = (const float*)d_in[3];
    const float* Wr1 = (const float*)d_in[4];
    const float* W2  = (const float*)d_in[5];
    const float* b2  = (const float*)d_in[6];
    const float* Wr2 = (const float*)d_in[7];

    int N = in_sizes[0] / FIN;
    int E = in_sizes[1] / 2;
    int NB = (N + 255) / 256;
    int K  = (N + 255) >> BSH;   // dst buckets

    char* ws = (char*)d_ws;
    size_t off = 0;
    auto alloc = [&](size_t bytes) {
        void* ptr = ws + off;
        off += (bytes + 511) / 512 * 512;
        return ptr;
    };
    int* deg               = (int*)alloc((size_t)N * sizeof(int));
    int* cursor            = (int*)alloc((size_t)N * sizeof(int));
    int* partial           = (int*)alloc((size_t)NB * sizeof(int));
    int* offsets           = (int*)alloc((size_t)NB * sizeof(int));
    int* gcur              = (int*)alloc((size_t)K * sizeof(int));
    int* bstart            = (int*)alloc((size_t)K * sizeof(int));
    int* adj               = (int*)alloc((size_t)E * sizeof(int));
    unsigned short* z10    = (unsigned short*)alloc((size_t)N * FHID * 2);
    unsigned short* r1     = (unsigned short*)alloc((size_t)N * FHID * 2);
    unsigned short* out1   = (unsigned short*)alloc((size_t)N * FHID * 2);
    int2* pairs            = (int2*)alloc((size_t)E * sizeof(int2));
    unsigned short* wcat1  = (unsigned short*)alloc(64 * 128 * 2);
    unsigned short* wcat2w = (unsigned short*)alloc(64 * 32 * 2);
    unsigned short* wcat2r = (unsigned short*)alloc(64 * 32 * 2);

    float* out = (float*)d_out;

    hipMemsetAsync(deg, 0, (size_t)N * sizeof(int), stream);

    int eb = (E + 255) / 256;
    k_prepack<<<1, 256, 0, stream>>>(W1, Wr1, W2, Wr2, wcat1, wcat2w, wcat2r);
    k_count<<<eb, 256, 0, stream>>>(ei, E, N, deg);
    k_blocksum<<<NB, 256, 0, stream>>>(deg, N, partial);
    k_scanpartial<<<1, 1024, 0, stream>>>(partial, NB, offsets);
    k_scandeg<<<NB, 256, 0, stream>>>(deg, N, offsets, cursor);
    k_initb<<<(K + 255) / 256, 256, 0, stream>>>(cursor, gcur, bstart, K);
    int nwgA = (E + ACHUNK - 1) / ACHUNK;
    k_passA<<<nwgA, 256, 0, stream>>>(ei, E, N, gcur, pairs);
    k_passB<<<K, 256, 0, stream>>>(pairs, gcur, bstart, deg, cursor, adj, N);

    int nb64 = (N + 63) / 64;     // MFMA pre kernel: 64 nodes per block
    int nbfx = (N + 255) / 256;   // fixup: wave scans 64 nodes

    k_pre1m<<<nb64, 256, 0, stream>>>(x, wcat1, b1, z10, r1, N);
    k_fix1<<<nbfx, 256, 0, stream>>>(x, deg, cursor, adj, W1, b1, Wr1, out1, N);
    k_layer1agg<<<K, 512, 0, stream>>>(z10, r1, deg, bstart, gcur, pairs, out1, N);
    k_layer2agg<<<K, 512, 0, stream>>>(out1, deg, bstart, gcur, pairs, wcat2w, wcat2r,
                                       W2, Wr2, b2, out, N);
}

// Round 3
// 391.430 us; speedup vs baseline: 2.6710x; 2.6710x over previous
//
#include <hip/hip_runtime.h>

#define FIN 128
#define FHID 32
#define FOUT 64
#define MAXDEG 10
#define BSH 8              // dst bucket = dst >> 8 (256 dsts per bucket)
#define ACHUNK 4096        // edges per pass-A workgroup (16 per thread)
#define XPAD 136           // LDS row stride (bf16) for 128-k tiles
#define YPAD 40            // LDS row stride (bf16) for 32-k tiles: 80B, 16B-aligned

typedef __attribute__((ext_vector_type(8))) short short8;
typedef __attribute__((ext_vector_type(4))) float f32x4;

// edge_index arrives as int32: layout [2, E] flat: src = ei[e], dst = ei[E + e].

__device__ __forceinline__ float bf2f(unsigned short u) {
    union { unsigned int i; float f; } c; c.i = ((unsigned int)u) << 16; return c.f;
}
__device__ __forceinline__ unsigned short f2bf(float f) {
    union { float f; unsigned int i; } c; c.f = f;
    unsigned int r = c.i + 0x7FFF + ((c.i >> 16) & 1);   // round-nearest-even
    return (unsigned short)(r >> 16);
}
__device__ __forceinline__ float bflo(unsigned int w) { return bf2f((unsigned short)(w & 0xffff)); }
__device__ __forceinline__ float bfhi(unsigned int w) { return bf2f((unsigned short)(w >> 16)); }
__device__ __forceinline__ unsigned int pk2(float lo, float hi) {
    return (unsigned int)f2bf(lo) | ((unsigned int)f2bf(hi) << 16);
}

// ---------- CSR build ----------

__global__ __launch_bounds__(256) void k_count(const int* __restrict__ ei, int E, int N,
                                               int* __restrict__ deg) {
    int e = blockIdx.x * 256 + threadIdx.x;
    if (e >= E) return;
    int d = ei[E + e];
    if ((unsigned)d < (unsigned)N) atomicAdd(deg + d, 1);
}

__global__ __launch_bounds__(256) void k_blocksum(const int* __restrict__ deg, int N,
                                                  int* __restrict__ partial) {
    __shared__ int tmp[256];
    int t = threadIdx.x;
    int i = blockIdx.x * 256 + t;
    tmp[t] = (i < N) ? deg[i] : 0;
    __syncthreads();
    for (int off = 128; off > 0; off >>= 1) {
        if (t < off) tmp[t] += tmp[t + off];
        __syncthreads();
    }
    if (t == 0) partial[blockIdx.x] = tmp[0];
}

// single-block exclusive scan of partial[0..NB) -> offsets   (requires NB <= 1024)
__global__ __launch_bounds__(1024) void k_scanpartial(const int* __restrict__ partial, int NB,
                                                      int* __restrict__ offsets) {
    __shared__ int tmp[1024];
    int t = threadIdx.x;
    int v = (t < NB) ? partial[t] : 0;
    tmp[t] = v;
    __syncthreads();
    for (int off = 1; off < 1024; off <<= 1) {
        int a = (t >= off) ? tmp[t - off] : 0;
        __syncthreads();
        tmp[t] += a;
        __syncthreads();
    }
    if (t < NB) offsets[t] = tmp[t] - v;
}

__global__ __launch_bounds__(256) void k_scandeg(const int* __restrict__ deg, int N,
                                                 const int* __restrict__ offsets,
                                                 int* __restrict__ cursor) {
    __shared__ int tmp[256];
    int t = threadIdx.x;
    int i = blockIdx.x * 256 + t;
    int v = (i < N) ? deg[i] : 0;
    tmp[t] = v;
    __syncthreads();
    for (int off = 1; off < 256; off <<= 1) {
        int a = (t >= off) ? tmp[t - off] : 0;
        __syncthreads();
        tmp[t] += a;
        __syncthreads();
    }
    if (i < N) cursor[i] = offsets[blockIdx.x] + tmp[t] - v;
}

// gcur[b] = adj start offset of bucket b (= row start of first dst in bucket)
__global__ __launch_bounds__(256) void k_initb(const int* __restrict__ cursor,
                                               int* __restrict__ gcur, int K) {
    int b = blockIdx.x * 256 + threadIdx.x;
    if (b < K) gcur[b] = cursor[b << BSH];
}

// Pass A: bucket edges by dst>>8 into pairs[], line-coalesced appends.
__global__ __launch_bounds__(256) void k_passA(const int* __restrict__ ei, int E, int N,
                                               int* __restrict__ gcur,
                                               int2* __restrict__ pairs) {
    __shared__ int hist[1024];
    __shared__ int base[1024];
    int K = ((N + 255) >> BSH);
    int t = threadIdx.x;
    long long cb = (long long)blockIdx.x * ACHUNK;
    for (int i = t; i < K; i += 256) hist[i] = 0;
    __syncthreads();
    int sv[16], dv[16];
#pragma unroll
    for (int i = 0; i < 16; ++i) {
        sv[i] = -1; dv[i] = 0;
        long long e = cb + t + (long long)i * 256;
        if (e < E) {
            int ss = ei[e];
            int dd = ei[E + e];
            if ((unsigned)ss < (unsigned)N && (unsigned)dd < (unsigned)N) {
                sv[i] = ss; dv[i] = dd;
            }
        }
    }
#pragma unroll
    for (int i = 0; i < 16; ++i)
        if (sv[i] >= 0) atomicAdd(&hist[dv[i] >> BSH], 1);
    __syncthreads();
    for (int i = t; i < K; i += 256) {
        int h = hist[i];
        base[i] = h ? atomicAdd(&gcur[i], h) : 0;
    }
    __syncthreads();
    for (int i = t; i < K; i += 256) hist[i] = 0;
    __syncthreads();
#pragma unroll
    for (int i = 0; i < 16; ++i) {
        if (sv[i] >= 0) {
            int b = dv[i] >> BSH;
            int off = atomicAdd(&hist[b], 1);
            pairs[base[b] + off] = make_int2(sv[i], dv[i]);
        }
    }
}

// Pass B: one workgroup per bucket; private LDS cursors; flushes row ends.
__global__ __launch_bounds__(256) void k_passB(const int2* __restrict__ pairs,
                                               const int* __restrict__ gcur,
                                               int* __restrict__ cursor,
                                               int* __restrict__ adj, int N) {
    __shared__ int cur[256];
    int b = blockIdx.x;
    int lo = b << BSH;
    int hi = min(lo + 256, N);
    int t = threadIdx.x;
    int cnt = hi - lo;
    if (t < cnt) cur[t] = cursor[lo + t];
    int pstart = cursor[lo];
    int pend = gcur[b];
    __syncthreads();
    for (int i = pstart + t; i < pend; i += 256) {
        int2 pr = pairs[i];
        int pos = atomicAdd(&cur[pr.y - lo], 1);
        adj[pos] = pr.x;
    }
    __syncthreads();
    if (t < cnt) cursor[lo + t] = cur[t];
}

// ---------- prepack bucket-10 weights as bf16, B-operand layout [n][k] ----------
// wcat1: [64 n][128 k]; n<32 -> W1[10][k][n], else Wr1[10][k][n-32]
// wcat2: [128 n][32 k]; n<64 -> W2[10][k][n], else Wr2[10][k][n-64]
__global__ __launch_bounds__(256) void k_prepack(const float* __restrict__ W1,
                                                 const float* __restrict__ Wr1,
                                                 const float* __restrict__ W2,
                                                 const float* __restrict__ Wr2,
                                                 unsigned short* __restrict__ wcat1,
                                                 unsigned short* __restrict__ wcat2) {
    int t = threadIdx.x;
    const float* W1b  = W1  + (size_t)MAXDEG * FIN * FHID;
    const float* Wr1b = Wr1 + (size_t)MAXDEG * FIN * FHID;
    const float* W2b  = W2  + (size_t)MAXDEG * FHID * FOUT;
    const float* Wr2b = Wr2 + (size_t)MAXDEG * FHID * FOUT;
    for (int i = 0; i < 32; ++i) {
        int idx = i * 256 + t;            // 8192
        int n = idx >> 7, k = idx & 127;
        float v = (n < 32) ? W1b[k * FHID + n] : Wr1b[k * FHID + (n - 32)];
        wcat1[idx] = f2bf(v);
    }
    for (int i = 0; i < 16; ++i) {
        int idx = i * 256 + t;            // 4096
        int n = idx >> 5, k = idx & 31;
        float v = (n < 64) ? W2b[k * FOUT + n] : Wr2b[k * FOUT + (n - 64)];
        wcat2[idx] = f2bf(v);
    }
}

// ---------- pre1 (MFMA): [z10 | r1] = x @ [W1[10] | Wr1[10]] + [0 | b1[10]] ----------
__global__ __launch_bounds__(256) void k_pre1m(const float* __restrict__ x,
                                               const unsigned short* __restrict__ wcat1,
                                               const float* __restrict__ b1,
                                               unsigned short* __restrict__ z10,
                                               unsigned short* __restrict__ r1, int N) {
    __shared__ __align__(16) unsigned short xt[64 * XPAD];
    __shared__ __align__(16) unsigned short wt[64 * XPAD];
    int t = threadIdx.x;
    int row0 = blockIdx.x * 64;
    {   // stage Wcat1 (8192 bf16 = 1024 uint4)
        const uint4* src = (const uint4*)wcat1;
#pragma unroll
        for (int i = 0; i < 4; ++i) {
            int idx = i * 256 + t;
            uint4 v = src[idx];
            int n = idx >> 4;
            int k = (idx & 15) * 8;
            *(uint4*)(wt + n * XPAD + k) = v;
        }
    }
    {   // stage x rows -> bf16
        int r = t >> 2;
        int c0 = (t & 3) * 32;
        int cr = min(row0 + r, N - 1);
        const float4* xs = (const float4*)(x + (size_t)cr * FIN + c0);
        unsigned short* dst = xt + r * XPAD + c0;
#pragma unroll
        for (int i = 0; i < 8; ++i) {
            float4 v = xs[i];
            ushort4 b;
            b.x = f2bf(v.x); b.y = f2bf(v.y); b.z = f2bf(v.z); b.w = f2bf(v.w);
            *(ushort4*)(dst + i * 4) = b;
        }
    }
    __syncthreads();
    int w = t >> 6, lane = t & 63;
    int m = lane & 15, quad = lane >> 4;
    const unsigned short* arow = xt + (w * 16 + m) * XPAD + quad * 8;
    short8 af[4];
#pragma unroll
    for (int kt = 0; kt < 4; ++kt) af[kt] = *(const short8*)(arow + kt * 32);
    f32x4 acc[4];
#pragma unroll
    for (int ct = 0; ct < 4; ++ct) acc[ct] = (f32x4){0.f, 0.f, 0.f, 0.f};
#pragma unroll
    for (int ct = 0; ct < 4; ++ct) {
        const unsigned short* brow = wt + (ct * 16 + m) * XPAD + quad * 8;
#pragma unroll
        for (int kt = 0; kt < 4; ++kt) {
            short8 bfr = *(const short8*)(brow + kt * 32);
            acc[ct] = __builtin_amdgcn_mfma_f32_16x16x32_bf16(af[kt], bfr, acc[ct], 0, 0, 0);
        }
    }
    int rbase = row0 + w * 16 + quad * 4;
#pragma unroll
    for (int ct = 0; ct < 4; ++ct) {
        float bias = (ct >= 2) ? b1[MAXDEG * FHID + (ct - 2) * 16 + m] : 0.f;
#pragma unroll
        for (int rg = 0; rg < 4; ++rg) {
            int n = rbase + rg;
            if (n < N) {
                float v = acc[ct][rg];
                if (ct < 2) z10[(size_t)n * FHID + ct * 16 + m] = f2bf(v);
                else        r1[(size_t)n * FHID + (ct - 2) * 16 + m] = f2bf(v + bias);
            }
        }
    }
}

// fixup+slow path for deg<10 nodes: full layer1 output via true-bucket weights.
__global__ __launch_bounds__(256) void k_fix1(const float* __restrict__ x,
                                              const int* __restrict__ deg,
                                              const int* __restrict__ cursor,
                                              const int* __restrict__ adj,
                                              const float* __restrict__ W1,
                                              const float* __restrict__ b1,
                                              const float* __restrict__ Wr1,
                                              unsigned short* __restrict__ out1, int N) {
    int wavebase = blockIdx.x * 256 + (threadIdx.x & 192);
    int lane = threadIdx.x & 63;
    int nl = wavebase + lane;
    bool fl = (nl < N) && (deg[nl] < MAXDEG);
    unsigned long long mask = __ballot(fl);
    int u = lane >> 5, o = lane & 31;
    while (mask) {
        int b = __ffsll(mask) - 1;
        mask &= mask - 1;
        int n = wavebase + b;
        int d = deg[n];
        // root term: Wr1[d]^T x_n  (split-K across halves u)
        const float* Wr = Wr1 + (size_t)d * (FIN * FHID) + o;
        const float4* xr = (const float4*)(x + (size_t)n * FIN);
        float racc = 0.f;
        for (int c = u * 16; c < u * 16 + 16; ++c) {
            float4 xv = xr[c];
            racc += xv.x * Wr[(c * 4 + 0) * FHID] + xv.y * Wr[(c * 4 + 1) * FHID]
                  + xv.z * Wr[(c * 4 + 2) * FHID] + xv.w * Wr[(c * 4 + 3) * FHID];
        }
        racc += __shfl_xor(racc, 32);
        // neighbor aggregate: h = sum x_j  (feats lane*2, lane*2+1 per lane)
        int e1 = cursor[n];
        int e0 = e1 - d;
        float2 h = make_float2(0.f, 0.f);
        for (int k = e0; k < e1; ++k) {
            int s = adj[k];
            float2 v = *(const float2*)(x + (size_t)s * FIN + lane * 2);
            h.x += v.x; h.y += v.y;
        }
        // transform: W1[d]^T h  (split-K across halves u)
        const float* Wp = W1 + (size_t)d * (FIN * FHID) + o;
        float acc = 0.f;
        for (int f = u * 64; f < u * 64 + 64; ++f) {
            float hf = __shfl((f & 1) ? h.y : h.x, f >> 1);
            acc += hf * Wp[f * FHID];
        }
        acc += __shfl_xor(acc, 32);
        if (lane < 32) {
            float rv = racc + b1[d * FHID + o];
            out1[(size_t)n * FHID + o] = f2bf(fmaxf(acc + rv, 0.f));
        }
    }
}

// ---------- 16-lane/edge gather core: lane = (edge e = lane>>4, feat-pair f2 = lane&15) ----------
// Returns per-lane partial sums a0,a1 for feats 2*f2, 2*f2+1 (pre-reduce).
__device__ __forceinline__ void gather16(const unsigned short* __restrict__ rows,
                                         const int* __restrict__ adj,
                                         int e0, int e1, int cnt, int lane,
                                         float& a0, float& a1) {
    int e = lane >> 4, f2 = lane & 15;
    int sidx = adj[min(e0 + lane, e1 - 1)];
    const unsigned short* rb = rows + f2 * 2;
    int nch = (cnt + 15) >> 4;
    for (int c = 0; c < nch; ++c) {
        int i0 = c * 16 + e;
        int i1 = i0 + 4, i2 = i0 + 8, i3 = i0 + 12;
        int s0 = __shfl(sidx, min(i0, cnt - 1));
        int s1 = __shfl(sidx, min(i1, cnt - 1));
        int s2 = __shfl(sidx, min(i2, cnt - 1));
        int s3 = __shfl(sidx, min(i3, cnt - 1));
        unsigned int w0 = *(const unsigned int*)(rb + (size_t)s0 * FHID);
        unsigned int w1 = *(const unsigned int*)(rb + (size_t)s1 * FHID);
        unsigned int w2 = *(const unsigned int*)(rb + (size_t)s2 * FHID);
        unsigned int w3 = *(const unsigned int*)(rb + (size_t)s3 * FHID);
        float c0 = (i0 < cnt) ? 1.f : 0.f;
        float c1 = (i1 < cnt) ? 1.f : 0.f;
        float c2 = (i2 < cnt) ? 1.f : 0.f;
        float c3 = (i3 < cnt) ? 1.f : 0.f;
        a0 = fmaf(c0, bflo(w0), a0); a1 = fmaf(c0, bfhi(w0), a1);
        a0 = fmaf(c1, bflo(w1), a0); a1 = fmaf(c1, bfhi(w1), a1);
        a0 = fmaf(c2, bflo(w2), a0); a1 = fmaf(c2, bfhi(w2), a1);
        a0 = fmaf(c3, bflo(w3), a0); a1 = fmaf(c3, bfhi(w3), a1);
    }
    for (int k = e0 + 64 + e; k < e1; k += 4) {    // rare tail (deg>64)
        int s = adj[k];
        unsigned int w = *(const unsigned int*)(rb + (size_t)s * FHID);
        a0 += bflo(w); a1 += bfhi(w);
    }
}

// ---------- layer1 fast path (deg>=10): gather z10, out1 = relu(h + r1) ----------
__global__ __launch_bounds__(256) void k_layer1b(const unsigned short* __restrict__ z10,
                                                 const unsigned short* __restrict__ r1,
                                                 const int* __restrict__ deg,
                                                 const int* __restrict__ cursor,
                                                 const int* __restrict__ adj,
                                                 unsigned short* __restrict__ out1, int N) {
    int wave = (int)(((long long)blockIdx.x * 256 + threadIdx.x) >> 6);
    if (wave >= N) return;
    int n = wave;
    int lane = threadIdx.x & 63;
    int dg = deg[n];
    if (dg < MAXDEG) return;           // handled by k_fix1
    int e1 = cursor[n];
    int e0 = e1 - dg;
    float a0 = 0.f, a1 = 0.f;
    gather16(z10, adj, e0, e1, min(dg, 64), lane, a0, a1);
    a0 += __shfl_xor(a0, 16); a1 += __shfl_xor(a1, 16);
    a0 += __shfl_xor(a0, 32); a1 += __shfl_xor(a1, 32);
    if (lane < 16) {
        int f2 = lane;
        unsigned int rv = *(const unsigned int*)(r1 + (size_t)n * FHID + f2 * 2);
        unsigned int w = pk2(fmaxf(a0 + bflo(rv), 0.f), fmaxf(a1 + bfhi(rv), 0.f));
        *(unsigned int*)(out1 + (size_t)n * FHID + f2 * 2) = w;
    }
}

// ---------- layer2 gather (ALL nodes): g[n] = sum_{j in N(n)} y_j  (f32) ----------
__global__ __launch_bounds__(256) void k_layer2g(const unsigned short* __restrict__ y,
                                                 const int* __restrict__ deg,
                                                 const int* __restrict__ cursor,
                                                 const int* __restrict__ adj,
                                                 float* __restrict__ g, int N) {
    int wave = (int)(((long long)blockIdx.x * 256 + threadIdx.x) >> 6);
    if (wave >= N) return;
    int n = wave;
    int lane = threadIdx.x & 63;
    int dg = deg[n];
    float a0 = 0.f, a1 = 0.f;
    if (dg > 0) {
        int e1 = cursor[n];
        int e0 = e1 - dg;
        gather16(y, adj, e0, e1, min(dg, 64), lane, a0, a1);
        a0 += __shfl_xor(a0, 16); a1 += __shfl_xor(a1, 16);
        a0 += __shfl_xor(a0, 32); a1 += __shfl_xor(a1, 32);
    }
    if (lane < 16) {
        *(float2*)(g + (size_t)n * FHID + lane * 2) = make_float2(a0, a1);
    }
}

// ---------- post2 (MFMA, dense): out = g @ W2[10] + y @ Wr2[10] + b2[10] ----------
__global__ __launch_bounds__(256) void k_post2m(const float* __restrict__ g,
                                                const unsigned short* __restrict__ y,
                                                const unsigned short* __restrict__ wcat2,
                                                const float* __restrict__ b2,
                                                float* __restrict__ out, int N) {
    __shared__ __align__(16) unsigned short gt[64 * YPAD];
    __shared__ __align__(16) unsigned short yt[64 * YPAD];
    __shared__ __align__(16) unsigned short wt[128 * YPAD];
    int t = threadIdx.x;
    int row0 = blockIdx.x * 64;
    {   // stage wcat2 (4096 bf16 = 512 uint4): [128 n][32 k]
        const uint4* src = (const uint4*)wcat2;
#pragma unroll
        for (int i = 0; i < 2; ++i) {
            int idx = i * 256 + t;
            uint4 v = src[idx];
            int nn = idx >> 2;
            int k = (idx & 3) * 8;
            *(uint4*)(wt + nn * YPAD + k) = v;
        }
    }
    {   // stage g rows (f32 -> bf16) and y rows (bf16)
        int r = t >> 2, c0 = (t & 3) * 8;
        int rn = min(row0 + r, N - 1);
        const float4* gs = (const float4*)(g + (size_t)rn * FHID + c0);
        float4 v0 = gs[0], v1 = gs[1];
        ushort4 p0, p1;
        p0.x = f2bf(v0.x); p0.y = f2bf(v0.y); p0.z = f2bf(v0.z); p0.w = f2bf(v0.w);
        p1.x = f2bf(v1.x); p1.y = f2bf(v1.y); p1.z = f2bf(v1.z); p1.w = f2bf(v1.w);
        *(ushort4*)(gt + r * YPAD + c0) = p0;
        *(ushort4*)(gt + r * YPAD + c0 + 4) = p1;
        uint4 vy = *(const uint4*)(y + (size_t)rn * FHID + c0);
        *(uint4*)(yt + r * YPAD + c0) = vy;
    }
    __syncthreads();
    int w = t >> 6, lane = t & 63;
    int m = lane & 15, quad = lane >> 4;
    short8 ag = *(const short8*)(gt + (w * 16 + m) * YPAD + quad * 8);
    short8 ay = *(const short8*)(yt + (w * 16 + m) * YPAD + quad * 8);
    int rbase = row0 + w * 16 + quad * 4;
#pragma unroll
    for (int ct = 0; ct < 4; ++ct) {
        short8 bw = *(const short8*)(wt + (ct * 16 + m) * YPAD + quad * 8);
        short8 br = *(const short8*)(wt + ((64 + ct * 16) + m) * YPAD + quad * 8);
        f32x4 acc = (f32x4){0.f, 0.f, 0.f, 0.f};
        acc = __builtin_amdgcn_mfma_f32_16x16x32_bf16(ag, bw, acc, 0, 0, 0);
        acc = __builtin_amdgcn_mfma_f32_16x16x32_bf16(ay, br, acc, 0, 0, 0);
        int o = ct * 16 + m;
        float bias = b2[MAXDEG * FOUT + o];
#pragma unroll
        for (int rg = 0; rg < 4; ++rg) {
            int nn = rbase + rg;
            if (nn < N) out[(size_t)nn * FOUT + o] = acc[rg] + bias;
        }
    }
}

// fixup: recompute out rows with true-bucket W2[d]/Wr2[d] for deg<10 nodes (exact f32 g).
__global__ __launch_bounds__(256) void k_fix2b(const float* __restrict__ g,
                                               const unsigned short* __restrict__ y,
                                               const int* __restrict__ deg,
                                               const float* __restrict__ b2,
                                               const float* __restrict__ W2,
                                               const float* __restrict__ Wr2,
                                               float* __restrict__ out, int N) {
    int wavebase = blockIdx.x * 256 + (threadIdx.x & 192);
    int lane = threadIdx.x & 63;
    int nl = wavebase + lane;
    bool fl = (nl < N) && (deg[nl] < MAXDEG);
    unsigned long long mask = __ballot(fl);
    while (mask) {
        int b = __ffsll(mask) - 1;
        mask &= mask - 1;
        int n = wavebase + b;
        int d = deg[n];
        const float* W2p  = W2  + (size_t)d * (FHID * FOUT) + lane;
        const float* Wr2p = Wr2 + (size_t)d * (FHID * FOUT) + lane;
        float2 gv = *(const float2*)(g + (size_t)n * FHID + (lane & 15) * 2);
        unsigned int yw = *(const unsigned int*)(y + (size_t)n * FHID + (lane & 15) * 2);
        float acc = b2[d * FOUT + lane];
#pragma unroll
        for (int q = 0; q < 16; ++q) {
            float g0 = __shfl(gv.x, q);
            float g1 = __shfl(gv.y, q);
            unsigned int yq = __shfl(yw, q);
            acc += g0 * W2p[(2 * q) * FOUT] + g1 * W2p[(2 * q + 1) * FOUT]
                 + bflo(yq) * Wr2p[(2 * q) * FOUT] + bfhi(yq) * Wr2p[(2 * q + 1) * FOUT];
        }
        out[(size_t)n * FOUT + lane] = acc;
    }
}

extern "C" void kernel_launch(void* const* d_in, const int* in_sizes, int n_in,
                              void* d_out, int out_size, void* d_ws, size_t ws_size,
                              hipStream_t stream) {
    const float* x   = (const float*)d_in[0];
    const int*   ei  = (const int*)d_in[1];   // int32, [2, E] flat
    const float* W1  = (const float*)d_in[2];
    const float* b1  = (const float*)d_in[3];
    const float* Wr1 = (const float*)d_in[4];
    const float* W2  = (const float*)d_in[5];
    const float* b2  = (const float*)d_in[6];
    const float* Wr2 = (const float*)d_in[7];

    int N = in_sizes[0] / FIN;
    int E = in_sizes[1] / 2;
    int NB = (N + 255) / 256;
    int K  = (N + 255) >> BSH;   // dst buckets

    char* ws = (char*)d_ws;
    size_t off = 0;
    auto alloc = [&](size_t bytes) {
        void* ptr = ws + off;
        off += (bytes + 511) / 512 * 512;
        return ptr;
    };
    int* deg              = (int*)alloc((size_t)N * sizeof(int));
    int* cursor           = (int*)alloc((size_t)N * sizeof(int));
    int* partial          = (int*)alloc((size_t)NB * sizeof(int));
    int* offsets          = (int*)alloc((size_t)NB * sizeof(int));
    int* gcur             = (int*)alloc((size_t)K * sizeof(int));
    int* adj              = (int*)alloc((size_t)E * sizeof(int));
    unsigned short* z10   = (unsigned short*)alloc((size_t)N * FHID * 2);
    unsigned short* r1    = (unsigned short*)alloc((size_t)N * FHID * 2);
    unsigned short* out1  = (unsigned short*)alloc((size_t)N * FHID * 2);
    // pairs (E*8B) and g (N*FHID*4B) share one region: pairs dead after k_passB,
    // g first written by k_layer2g which runs later.
    size_t pairsB = (size_t)E * sizeof(int2);
    size_t gB     = (size_t)N * FHID * sizeof(float);
    void* shared_region   = alloc(pairsB > gB ? pairsB : gB);
    float* g              = (float*)shared_region;
    int2* pairs           = (int2*)shared_region;
    unsigned short* wcat1 = (unsigned short*)alloc(64 * 128 * 2);
    unsigned short* wcat2 = (unsigned short*)alloc(128 * 32 * 2);

    float* out = (float*)d_out;

    hipMemsetAsync(deg, 0, (size_t)N * sizeof(int), stream);

    int eb = (E + 255) / 256;
    k_prepack<<<1, 256, 0, stream>>>(W1, Wr1, W2, Wr2, wcat1, wcat2);
    k_count<<<eb, 256, 0, stream>>>(ei, E, N, deg);
    k_blocksum<<<NB, 256, 0, stream>>>(deg, N, partial);
    k_scanpartial<<<1, 1024, 0, stream>>>(partial, NB, offsets);
    k_scandeg<<<NB, 256, 0, stream>>>(deg, N, offsets, cursor);
    k_initb<<<(K + 255) / 256, 256, 0, stream>>>(cursor, gcur, K);
    int nwgA = (E + ACHUNK - 1) / ACHUNK;
    k_passA<<<nwgA, 256, 0, stream>>>(ei, E, N, gcur, pairs);
    k_passB<<<K, 256, 0, stream>>>(pairs, gcur, cursor, adj, N);

    int nb64 = (N + 63) / 64;     // MFMA kernels: 64 nodes per block
    int nbfx = (N + 255) / 256;   // fixups: wave scans 64 nodes
    int nb_node = (N + 3) / 4;    // gather kernels: wave per node

    k_pre1m<<<nb64, 256, 0, stream>>>(x, wcat1, b1, z10, r1, N);
    k_fix1<<<nbfx, 256, 0, stream>>>(x, deg, cursor, adj, W1, b1, Wr1, out1, N);
    k_layer1b<<<nb_node, 256, 0, stream>>>(z10, r1, deg, cursor, adj, out1, N);
    k_layer2g<<<nb_node, 256, 0, stream>>>(out1, deg, cursor, adj, g, N);
    k_post2m<<<nb64, 256, 0, stream>>>(g, out1, wcat2, b2, out, N);
    k_fix2b<<<nbfx, 256, 0, stream>>>(g, out1, deg, b2, W2, Wr2, out, N);
}

// Round 4
// 336.701 us; speedup vs baseline: 3.1051x; 1.1625x over previous
//
#include <hip/hip_runtime.h>

#define FIN 128
#define FHID 32
#define FOUT 64
#define MAXDEG 10
#define BSH 8              // dst bucket = dst >> 8 (256 dsts per bucket)
#define ACHUNK 4096        // edges per pass-A workgroup (16 per thread)
#define XPAD 136           // LDS row stride (bf16) for 128-k tiles
#define YPAD 40            // LDS row stride (bf16) for 32-k tiles: 80B, 16B-aligned

typedef __attribute__((ext_vector_type(8))) short short8;
typedef __attribute__((ext_vector_type(4))) float f32x4;

// edge_index arrives as int32: layout [2, E] flat: src = ei[e], dst = ei[E + e].

__device__ __forceinline__ float bf2f(unsigned short u) {
    union { unsigned int i; float f; } c; c.i = ((unsigned int)u) << 16; return c.f;
}
__device__ __forceinline__ unsigned short f2bf(float f) {
    union { float f; unsigned int i; } c; c.f = f;
    unsigned int r = c.i + 0x7FFF + ((c.i >> 16) & 1);   // round-nearest-even
    return (unsigned short)(r >> 16);
}
__device__ __forceinline__ float bflo(unsigned int w) { return bf2f((unsigned short)(w & 0xffff)); }
__device__ __forceinline__ float bfhi(unsigned int w) { return bf2f((unsigned short)(w >> 16)); }
__device__ __forceinline__ unsigned int pk2(float lo, float hi) {
    return (unsigned int)f2bf(lo) | ((unsigned int)f2bf(hi) << 16);
}

// ---------- CSR build (bucket-hierarchical: NO per-edge global atomics) ----------

// Per-block LDS histogram over dst buckets; one global atomic per (block, bucket).
__global__ __launch_bounds__(256) void k_bhist(const int* __restrict__ ei, int E, int N,
                                               int* __restrict__ bcnt) {
    __shared__ int hist[1024];
    int K = ((N + 255) >> BSH);
    int t = threadIdx.x;
    long long cb = (long long)blockIdx.x * ACHUNK;
    for (int i = t; i < K; i += 256) hist[i] = 0;
    __syncthreads();
#pragma unroll
    for (int i = 0; i < 16; ++i) {
        long long e = cb + t + (long long)i * 256;
        if (e < E) {
            int ss = ei[e];
            int dd = ei[E + e];
            if ((unsigned)ss < (unsigned)N && (unsigned)dd < (unsigned)N)
                atomicAdd(&hist[dd >> BSH], 1);
        }
    }
    __syncthreads();
    for (int i = t; i < K; i += 256) {
        int h = hist[i];
        if (h) atomicAdd(&bcnt[i], h);
    }
}

// Single-block exclusive scan of bcnt[0..K) -> bstart, gcur  (requires K <= 1024).
__global__ __launch_bounds__(1024) void k_scanb(const int* __restrict__ bcnt, int K,
                                                int* __restrict__ bstart,
                                                int* __restrict__ gcur) {
    __shared__ int tmp[1024];
    int t = threadIdx.x;
    int v = (t < K) ? bcnt[t] : 0;
    tmp[t] = v;
    __syncthreads();
    for (int off = 1; off < 1024; off <<= 1) {
        int a = (t >= off) ? tmp[t - off] : 0;
        __syncthreads();
        tmp[t] += a;
        __syncthreads();
    }
    if (t < K) { int s = tmp[t] - v; bstart[t] = s; gcur[t] = s; }
}

// Pass A: bucket edges by dst>>8 into pairs[], line-coalesced appends.
__global__ __launch_bounds__(256) void k_passA(const int* __restrict__ ei, int E, int N,
                                               int* __restrict__ gcur,
                                               int2* __restrict__ pairs) {
    __shared__ int hist[1024];
    __shared__ int base[1024];
    int K = ((N + 255) >> BSH);
    int t = threadIdx.x;
    long long cb = (long long)blockIdx.x * ACHUNK;
    for (int i = t; i < K; i += 256) hist[i] = 0;
    __syncthreads();
    int sv[16], dv[16];
#pragma unroll
    for (int i = 0; i < 16; ++i) {
        sv[i] = -1; dv[i] = 0;
        long long e = cb + t + (long long)i * 256;
        if (e < E) {
            int ss = ei[e];
            int dd = ei[E + e];
            if ((unsigned)ss < (unsigned)N && (unsigned)dd < (unsigned)N) {
                sv[i] = ss; dv[i] = dd;
            }
        }
    }
#pragma unroll
    for (int i = 0; i < 16; ++i)
        if (sv[i] >= 0) atomicAdd(&hist[dv[i] >> BSH], 1);
    __syncthreads();
    for (int i = t; i < K; i += 256) {
        int h = hist[i];
        base[i] = h ? atomicAdd(&gcur[i], h) : 0;
    }
    __syncthreads();
    for (int i = t; i < K; i += 256) hist[i] = 0;
    __syncthreads();
#pragma unroll
    for (int i = 0; i < 16; ++i) {
        if (sv[i] >= 0) {
            int b = dv[i] >> BSH;
            int off = atomicAdd(&hist[b], 1);
            pairs[base[b] + off] = make_int2(sv[i], dv[i]);
        }
    }
}

// Pass B2: per bucket -- derive per-node degrees in LDS (no global atomics),
// in-LDS exclusive scan -> row starts, write deg/cursor, then scatter pairs->adj.
__global__ __launch_bounds__(256) void k_passB2(const int2* __restrict__ pairs,
                                                const int* __restrict__ bstart,
                                                const int* __restrict__ gcur,
                                                int* __restrict__ deg,
                                                int* __restrict__ cursor,
                                                int* __restrict__ adj, int N) {
    __shared__ int cnt[256];
    __shared__ int scn[256];
    __shared__ int cur[256];
    int b = blockIdx.x;
    int lo = b << BSH;
    int t = threadIdx.x;
    int nvalid = min(256, N - lo);
    cnt[t] = 0;
    int pstart = bstart[b];
    int pend = gcur[b];
    __syncthreads();
    for (int i = pstart + t; i < pend; i += 256)
        atomicAdd(&cnt[pairs[i].y - lo], 1);
    __syncthreads();
    int v = cnt[t];
    scn[t] = v;
    __syncthreads();
    for (int off = 1; off < 256; off <<= 1) {
        int a = (t >= off) ? scn[t - off] : 0;
        __syncthreads();
        scn[t] += a;
        __syncthreads();
    }
    int rowstart = pstart + scn[t] - v;
    cur[t] = rowstart;
    if (t < nvalid) { deg[lo + t] = v; cursor[lo + t] = rowstart + v; }   // cursor = row END
    __syncthreads();
    for (int i = pstart + t; i < pend; i += 256) {
        int2 pr = pairs[i];
        int pos = atomicAdd(&cur[pr.y - lo], 1);
        adj[pos] = pr.x;
    }
}

// ---------- prepack bucket-10 weights as bf16, B-operand layout [n][k] ----------
// wcat1: [64 n][128 k]; n<32 -> W1[10][k][n], else Wr1[10][k][n-32]
// wcat2: [128 n][32 k]; n<64 -> W2[10][k][n], else Wr2[10][k][n-64]
__global__ __launch_bounds__(256) void k_prepack(const float* __restrict__ W1,
                                                 const float* __restrict__ Wr1,
                                                 const float* __restrict__ W2,
                                                 const float* __restrict__ Wr2,
                                                 unsigned short* __restrict__ wcat1,
                                                 unsigned short* __restrict__ wcat2) {
    int t = threadIdx.x;
    const float* W1b  = W1  + (size_t)MAXDEG * FIN * FHID;
    const float* Wr1b = Wr1 + (size_t)MAXDEG * FIN * FHID;
    const float* W2b  = W2  + (size_t)MAXDEG * FHID * FOUT;
    const float* Wr2b = Wr2 + (size_t)MAXDEG * FHID * FOUT;
    for (int i = 0; i < 32; ++i) {
        int idx = i * 256 + t;            // 8192
        int n = idx >> 7, k = idx & 127;
        float v = (n < 32) ? W1b[k * FHID + n] : Wr1b[k * FHID + (n - 32)];
        wcat1[idx] = f2bf(v);
    }
    for (int i = 0; i < 16; ++i) {
        int idx = i * 256 + t;            // 4096
        int n = idx >> 5, k = idx & 31;
        float v = (n < 64) ? W2b[k * FOUT + n] : Wr2b[k * FOUT + (n - 64)];
        wcat2[idx] = f2bf(v);
    }
}

// ---------- pre1 (MFMA): [z10 | r1] = x @ [W1[10] | Wr1[10]] + [0 | b1[10]] ----------
__global__ __launch_bounds__(256) void k_pre1m(const float* __restrict__ x,
                                               const unsigned short* __restrict__ wcat1,
                                               const float* __restrict__ b1,
                                               unsigned short* __restrict__ z10,
                                               unsigned short* __restrict__ r1, int N) {
    __shared__ __align__(16) unsigned short xt[64 * XPAD];
    __shared__ __align__(16) unsigned short wt[64 * XPAD];
    int t = threadIdx.x;
    int row0 = blockIdx.x * 64;
    {   // stage Wcat1 (8192 bf16 = 1024 uint4)
        const uint4* src = (const uint4*)wcat1;
#pragma unroll
        for (int i = 0; i < 4; ++i) {
            int idx = i * 256 + t;
            uint4 v = src[idx];
            int n = idx >> 4;
            int k = (idx & 15) * 8;
            *(uint4*)(wt + n * XPAD + k) = v;
        }
    }
    {   // stage x rows -> bf16
        int r = t >> 2;
        int c0 = (t & 3) * 32;
        int cr = min(row0 + r, N - 1);
        const float4* xs = (const float4*)(x + (size_t)cr * FIN + c0);
        unsigned short* dst = xt + r * XPAD + c0;
#pragma unroll
        for (int i = 0; i < 8; ++i) {
            float4 v = xs[i];
            ushort4 b;
            b.x = f2bf(v.x); b.y = f2bf(v.y); b.z = f2bf(v.z); b.w = f2bf(v.w);
            *(ushort4*)(dst + i * 4) = b;
        }
    }
    __syncthreads();
    int w = t >> 6, lane = t & 63;
    int m = lane & 15, quad = lane >> 4;
    const unsigned short* arow = xt + (w * 16 + m) * XPAD + quad * 8;
    short8 af[4];
#pragma unroll
    for (int kt = 0; kt < 4; ++kt) af[kt] = *(const short8*)(arow + kt * 32);
    f32x4 acc[4];
#pragma unroll
    for (int ct = 0; ct < 4; ++ct) acc[ct] = (f32x4){0.f, 0.f, 0.f, 0.f};
#pragma unroll
    for (int ct = 0; ct < 4; ++ct) {
        const unsigned short* brow = wt + (ct * 16 + m) * XPAD + quad * 8;
#pragma unroll
        for (int kt = 0; kt < 4; ++kt) {
            short8 bfr = *(const short8*)(brow + kt * 32);
            acc[ct] = __builtin_amdgcn_mfma_f32_16x16x32_bf16(af[kt], bfr, acc[ct], 0, 0, 0);
        }
    }
    int rbase = row0 + w * 16 + quad * 4;
#pragma unroll
    for (int ct = 0; ct < 4; ++ct) {
        float bias = (ct >= 2) ? b1[MAXDEG * FHID + (ct - 2) * 16 + m] : 0.f;
#pragma unroll
        for (int rg = 0; rg < 4; ++rg) {
            int n = rbase + rg;
            if (n < N) {
                float v = acc[ct][rg];
                if (ct < 2) z10[(size_t)n * FHID + ct * 16 + m] = f2bf(v);
                else        r1[(size_t)n * FHID + (ct - 2) * 16 + m] = f2bf(v + bias);
            }
        }
    }
}

// fixup+slow path for deg<10 nodes: full layer1 output via true-bucket weights.
__global__ __launch_bounds__(256) void k_fix1(const float* __restrict__ x,
                                              const int* __restrict__ deg,
                                              const int* __restrict__ cursor,
                                              const int* __restrict__ adj,
                                              const float* __restrict__ W1,
                                              const float* __restrict__ b1,
                                              const float* __restrict__ Wr1,
                                              unsigned short* __restrict__ out1, int N) {
    int wavebase = blockIdx.x * 256 + (threadIdx.x & 192);
    int lane = threadIdx.x & 63;
    int nl = wavebase + lane;
    bool fl = (nl < N) && (deg[nl] < MAXDEG);
    unsigned long long mask = __ballot(fl);
    int u = lane >> 5, o = lane & 31;
    while (mask) {
        int b = __ffsll(mask) - 1;
        mask &= mask - 1;
        int n = wavebase + b;
        int d = deg[n];
        // root term: Wr1[d]^T x_n  (split-K across halves u)
        const float* Wr = Wr1 + (size_t)d * (FIN * FHID) + o;
        const float4* xr = (const float4*)(x + (size_t)n * FIN);
        float racc = 0.f;
        for (int c = u * 16; c < u * 16 + 16; ++c) {
            float4 xv = xr[c];
            racc += xv.x * Wr[(c * 4 + 0) * FHID] + xv.y * Wr[(c * 4 + 1) * FHID]
                  + xv.z * Wr[(c * 4 + 2) * FHID] + xv.w * Wr[(c * 4 + 3) * FHID];
        }
        racc += __shfl_xor(racc, 32);
        // neighbor aggregate: h = sum x_j  (feats lane*2, lane*2+1 per lane)
        int e1 = cursor[n];
        int e0 = e1 - d;
        float2 h = make_float2(0.f, 0.f);
        for (int k = e0; k < e1; ++k) {
            int s = adj[k];
            float2 v = *(const float2*)(x + (size_t)s * FIN + lane * 2);
            h.x += v.x; h.y += v.y;
        }
        // transform: W1[d]^T h  (split-K across halves u)
        const float* Wp = W1 + (size_t)d * (FIN * FHID) + o;
        float acc = 0.f;
        for (int f = u * 64; f < u * 64 + 64; ++f) {
            float hf = __shfl((f & 1) ? h.y : h.x, f >> 1);
            acc += hf * Wp[f * FHID];
        }
        acc += __shfl_xor(acc, 32);
        if (lane < 32) {
            float rv = racc + b1[d * FHID + o];
            out1[(size_t)n * FHID + o] = f2bf(fmaxf(acc + rv, 0.f));
        }
    }
}

// ---------- 16-lane/edge gather core: lane = (edge e = lane>>4, feat-pair f2 = lane&15) ----------
// Returns per-lane partial sums a0,a1 for feats 2*f2, 2*f2+1 (pre-reduce).
__device__ __forceinline__ void gather16(const unsigned short* __restrict__ rows,
                                         const int* __restrict__ adj,
                                         int e0, int e1, int cnt, int lane,
                                         float& a0, float& a1) {
    int e = lane >> 4, f2 = lane & 15;
    int sidx = adj[min(e0 + lane, e1 - 1)];
    const unsigned short* rb = rows + f2 * 2;
    int nch = (cnt + 15) >> 4;
    for (int c = 0; c < nch; ++c) {
        int i0 = c * 16 + e;
        int i1 = i0 + 4, i2 = i0 + 8, i3 = i0 + 12;
        int s0 = __shfl(sidx, min(i0, cnt - 1));
        int s1 = __shfl(sidx, min(i1, cnt - 1));
        int s2 = __shfl(sidx, min(i2, cnt - 1));
        int s3 = __shfl(sidx, min(i3, cnt - 1));
        unsigned int w0 = *(const unsigned int*)(rb + (size_t)s0 * FHID);
        unsigned int w1 = *(const unsigned int*)(rb + (size_t)s1 * FHID);
        unsigned int w2 = *(const unsigned int*)(rb + (size_t)s2 * FHID);
        unsigned int w3 = *(const unsigned int*)(rb + (size_t)s3 * FHID);
        float c0 = (i0 < cnt) ? 1.f : 0.f;
        float c1 = (i1 < cnt) ? 1.f : 0.f;
        float c2 = (i2 < cnt) ? 1.f : 0.f;
        float c3 = (i3 < cnt) ? 1.f : 0.f;
        a0 = fmaf(c0, bflo(w0), a0); a1 = fmaf(c0, bfhi(w0), a1);
        a0 = fmaf(c1, bflo(w1), a0); a1 = fmaf(c1, bfhi(w1), a1);
        a0 = fmaf(c2, bflo(w2), a0); a1 = fmaf(c2, bfhi(w2), a1);
        a0 = fmaf(c3, bflo(w3), a0); a1 = fmaf(c3, bfhi(w3), a1);
    }
    for (int k = e0 + 64 + e; k < e1; k += 4) {    // rare tail (deg>64)
        int s = adj[k];
        unsigned int w = *(const unsigned int*)(rb + (size_t)s * FHID);
        a0 += bflo(w); a1 += bfhi(w);
    }
}

// ---------- layer1 fast path (deg>=10): gather z10, out1 = relu(h + r1) ----------
__global__ __launch_bounds__(256) void k_layer1b(const unsigned short* __restrict__ z10,
                                                 const unsigned short* __restrict__ r1,
                                                 const int* __restrict__ deg,
                                                 const int* __restrict__ cursor,
                                                 const int* __restrict__ adj,
                                                 unsigned short* __restrict__ out1, int N) {
    int wave = (int)(((long long)blockIdx.x * 256 + threadIdx.x) >> 6);
    if (wave >= N) return;
    int n = wave;
    int lane = threadIdx.x & 63;
    int dg = deg[n];
    if (dg < MAXDEG) return;           // handled by k_fix1
    int e1 = cursor[n];
    int e0 = e1 - dg;
    float a0 = 0.f, a1 = 0.f;
    gather16(z10, adj, e0, e1, min(dg, 64), lane, a0, a1);
    a0 += __shfl_xor(a0, 16); a1 += __shfl_xor(a1, 16);
    a0 += __shfl_xor(a0, 32); a1 += __shfl_xor(a1, 32);
    if (lane < 16) {
        int f2 = lane;
        unsigned int rv = *(const unsigned int*)(r1 + (size_t)n * FHID + f2 * 2);
        unsigned int w = pk2(fmaxf(a0 + bflo(rv), 0.f), fmaxf(a1 + bfhi(rv), 0.f));
        *(unsigned int*)(out1 + (size_t)n * FHID + f2 * 2) = w;
    }
}

// ---------- layer2 gather (ALL nodes): g[n] = sum_{j in N(n)} y_j  (f32) ----------
__global__ __launch_bounds__(256) void k_layer2g(const unsigned short* __restrict__ y,
                                                 const int* __restrict__ deg,
                                                 const int* __restrict__ cursor,
                                                 const int* __restrict__ adj,
                                                 float* __restrict__ g, int N) {
    int wave = (int)(((long long)blockIdx.x * 256 + threadIdx.x) >> 6);
    if (wave >= N) return;
    int n = wave;
    int lane = threadIdx.x & 63;
    int dg = deg[n];
    float a0 = 0.f, a1 = 0.f;
    if (dg > 0) {
        int e1 = cursor[n];
        int e0 = e1 - dg;
        gather16(y, adj, e0, e1, min(dg, 64), lane, a0, a1);
        a0 += __shfl_xor(a0, 16); a1 += __shfl_xor(a1, 16);
        a0 += __shfl_xor(a0, 32); a1 += __shfl_xor(a1, 32);
    }
    if (lane < 16) {
        *(float2*)(g + (size_t)n * FHID + lane * 2) = make_float2(a0, a1);
    }
}

// ---------- post2 (MFMA, dense): out = g @ W2[10] + y @ Wr2[10] + b2[10] ----------
__global__ __launch_bounds__(256) void k_post2m(const float* __restrict__ g,
                                                const unsigned short* __restrict__ y,
                                                const unsigned short* __restrict__ wcat2,
                                                const float* __restrict__ b2,
                                                float* __restrict__ out, int N) {
    __shared__ __align__(16) unsigned short gt[64 * YPAD];
    __shared__ __align__(16) unsigned short yt[64 * YPAD];
    __shared__ __align__(16) unsigned short wt[128 * YPAD];
    int t = threadIdx.x;
    int row0 = blockIdx.x * 64;
    {   // stage wcat2 (4096 bf16 = 512 uint4): [128 n][32 k]
        const uint4* src = (const uint4*)wcat2;
#pragma unroll
        for (int i = 0; i < 2; ++i) {
            int idx = i * 256 + t;
            uint4 v = src[idx];
            int nn = idx >> 2;
            int k = (idx & 3) * 8;
            *(uint4*)(wt + nn * YPAD + k) = v;
        }
    }
    {   // stage g rows (f32 -> bf16) and y rows (bf16)
        int r = t >> 2, c0 = (t & 3) * 8;
        int rn = min(row0 + r, N - 1);
        const float4* gs = (const float4*)(g + (size_t)rn * FHID + c0);
        float4 v0 = gs[0], v1 = gs[1];
        ushort4 p0, p1;
        p0.x = f2bf(v0.x); p0.y = f2bf(v0.y); p0.z = f2bf(v0.z); p0.w = f2bf(v0.w);
        p1.x = f2bf(v1.x); p1.y = f2bf(v1.y); p1.z = f2bf(v1.z); p1.w = f2bf(v1.w);
        *(ushort4*)(gt + r * YPAD + c0) = p0;
        *(ushort4*)(gt + r * YPAD + c0 + 4) = p1;
        uint4 vy = *(const uint4*)(y + (size_t)rn * FHID + c0);
        *(uint4*)(yt + r * YPAD + c0) = vy;
    }
    __syncthreads();
    int w = t >> 6, lane = t & 63;
    int m = lane & 15, quad = lane >> 4;
    short8 ag = *(const short8*)(gt + (w * 16 + m) * YPAD + quad * 8);
    short8 ay = *(const short8*)(yt + (w * 16 + m) * YPAD + quad * 8);
    int rbase = row0 + w * 16 + quad * 4;
#pragma unroll
    for (int ct = 0; ct < 4; ++ct) {
        short8 bw = *(const short8*)(wt + (ct * 16 + m) * YPAD + quad * 8);
        short8 br = *(const short8*)(wt + ((64 + ct * 16) + m) * YPAD + quad * 8);
        f32x4 acc = (f32x4){0.f, 0.f, 0.f, 0.f};
        acc = __builtin_amdgcn_mfma_f32_16x16x32_bf16(ag, bw, acc, 0, 0, 0);
        acc = __builtin_amdgcn_mfma_f32_16x16x32_bf16(ay, br, acc, 0, 0, 0);
        int o = ct * 16 + m;
        float bias = b2[MAXDEG * FOUT + o];
#pragma unroll
        for (int rg = 0; rg < 4; ++rg) {
            int nn = rbase + rg;
            if (nn < N) out[(size_t)nn * FOUT + o] = acc[rg] + bias;
        }
    }
}

// fixup: recompute out rows with true-bucket W2[d]/Wr2[d] for deg<10 nodes (exact f32 g).
__global__ __launch_bounds__(256) void k_fix2b(const float* __restrict__ g,
                                               const unsigned short* __restrict__ y,
                                               const int* __restrict__ deg,
                                               const float* __restrict__ b2,
                                               const float* __restrict__ W2,
                                               const float* __restrict__ Wr2,
                                               float* __restrict__ out, int N) {
    int wavebase = blockIdx.x * 256 + (threadIdx.x & 192);
    int lane = threadIdx.x & 63;
    int nl = wavebase + lane;
    bool fl = (nl < N) && (deg[nl] < MAXDEG);
    unsigned long long mask = __ballot(fl);
    while (mask) {
        int b = __ffsll(mask) - 1;
        mask &= mask - 1;
        int n = wavebase + b;
        int d = deg[n];
        const float* W2p  = W2  + (size_t)d * (FHID * FOUT) + lane;
        const float* Wr2p = Wr2 + (size_t)d * (FHID * FOUT) + lane;
        float2 gv = *(const float2*)(g + (size_t)n * FHID + (lane & 15) * 2);
        unsigned int yw = *(const unsigned int*)(y + (size_t)n * FHID + (lane & 15) * 2);
        float acc = b2[d * FOUT + lane];
#pragma unroll
        for (int q = 0; q < 16; ++q) {
            float g0 = __shfl(gv.x, q);
            float g1 = __shfl(gv.y, q);
            unsigned int yq = __shfl(yw, q);
            acc += g0 * W2p[(2 * q) * FOUT] + g1 * W2p[(2 * q + 1) * FOUT]
                 + bflo(yq) * Wr2p[(2 * q) * FOUT] + bfhi(yq) * Wr2p[(2 * q + 1) * FOUT];
        }
        out[(size_t)n * FOUT + lane] = acc;
    }
}

extern "C" void kernel_launch(void* const* d_in, const int* in_sizes, int n_in,
                              void* d_out, int out_size, void* d_ws, size_t ws_size,
                              hipStream_t stream) {
    const float* x   = (const float*)d_in[0];
    const int*   ei  = (const int*)d_in[1];   // int32, [2, E] flat
    const float* W1  = (const float*)d_in[2];
    const float* b1  = (const float*)d_in[3];
    const float* Wr1 = (const float*)d_in[4];
    const float* W2  = (const float*)d_in[5];
    const float* b2  = (const float*)d_in[6];
    const float* Wr2 = (const float*)d_in[7];

    int N = in_sizes[0] / FIN;
    int E = in_sizes[1] / 2;
    int K  = (N + 255) >> BSH;   // dst buckets

    char* ws = (char*)d_ws;
    size_t off = 0;
    auto alloc = [&](size_t bytes) {
        void* ptr = ws + off;
        off += (bytes + 511) / 512 * 512;
        return ptr;
    };
    int* deg              = (int*)alloc((size_t)N * sizeof(int));
    int* cursor           = (int*)alloc((size_t)N * sizeof(int));
    int* bcnt             = (int*)alloc((size_t)K * sizeof(int));
    int* bstart           = (int*)alloc((size_t)K * sizeof(int));
    int* gcur             = (int*)alloc((size_t)K * sizeof(int));
    int* adj              = (int*)alloc((size_t)E * sizeof(int));
    unsigned short* z10   = (unsigned short*)alloc((size_t)N * FHID * 2);
    unsigned short* r1    = (unsigned short*)alloc((size_t)N * FHID * 2);
    unsigned short* out1  = (unsigned short*)alloc((size_t)N * FHID * 2);
    // pairs (E*8B) and g (N*FHID*4B) share one region: pairs dead after k_passB2,
    // g first written by k_layer2g which runs later.
    size_t pairsB = (size_t)E * sizeof(int2);
    size_t gB     = (size_t)N * FHID * sizeof(float);
    void* shared_region   = alloc(pairsB > gB ? pairsB : gB);
    float* g              = (float*)shared_region;
    int2* pairs           = (int2*)shared_region;
    unsigned short* wcat1 = (unsigned short*)alloc(64 * 128 * 2);
    unsigned short* wcat2 = (unsigned short*)alloc(128 * 32 * 2);

    float* out = (float*)d_out;

    hipMemsetAsync(bcnt, 0, (size_t)K * sizeof(int), stream);

    int nwgA = (E + ACHUNK - 1) / ACHUNK;
    k_prepack<<<1, 256, 0, stream>>>(W1, Wr1, W2, Wr2, wcat1, wcat2);
    k_bhist<<<nwgA, 256, 0, stream>>>(ei, E, N, bcnt);
    k_scanb<<<1, 1024, 0, stream>>>(bcnt, K, bstart, gcur);
    k_passA<<<nwgA, 256, 0, stream>>>(ei, E, N, gcur, pairs);
    k_passB2<<<K, 256, 0, stream>>>(pairs, bstart, gcur, deg, cursor, adj, N);

    int nb64 = (N + 63) / 64;     // MFMA kernels: 64 nodes per block
    int nbfx = (N + 255) / 256;   // fixups: wave scans 64 nodes
    int nb_node = (N + 3) / 4;    // gather kernels: wave per node

    k_pre1m<<<nb64, 256, 0, stream>>>(x, wcat1, b1, z10, r1, N);
    k_fix1<<<nbfx, 256, 0, stream>>>(x, deg, cursor, adj, W1, b1, Wr1, out1, N);
    k_layer1b<<<nb_node, 256, 0, stream>>>(z10, r1, deg, cursor, adj, out1, N);
    k_layer2g<<<nb_node, 256, 0, stream>>>(out1, deg, cursor, adj, g, N);
    k_post2m<<<nb64, 256, 0, stream>>>(g, out1, wcat2, b2, out, N);
    k_fix2b<<<nbfx, 256, 0, stream>>>(g, out1, deg, b2, W2, Wr2, out, N);
}

// Round 5
// 294.164 us; speedup vs baseline: 3.5541x; 1.1446x over previous
//
#include <hip/hip_runtime.h>

#define FIN 128
#define FHID 32
#define FOUT 64
#define MAXDEG 10
#define BSH 8              // dst bucket = dst >> 8 (256 dsts per bucket)
#define ACHUNK 4096        // edges per pass-A workgroup (16 per thread)
#define XPAD 136           // LDS row stride (bf16) for 128-k tiles
#define YPAD 40            // LDS row stride (bf16) for 32-k tiles: 80B, 16B-aligned

typedef __attribute__((ext_vector_type(8))) short short8;
typedef __attribute__((ext_vector_type(4))) float f32x4;

// edge_index arrives as int32: layout [2, E] flat: src = ei[e], dst = ei[E + e].

__device__ __forceinline__ float bf2f(unsigned short u) {
    union { unsigned int i; float f; } c; c.i = ((unsigned int)u) << 16; return c.f;
}
__device__ __forceinline__ unsigned short f2bf(float f) {
    union { float f; unsigned int i; } c; c.f = f;
    unsigned int r = c.i + 0x7FFF + ((c.i >> 16) & 1);   // round-nearest-even
    return (unsigned short)(r >> 16);
}
__device__ __forceinline__ float bflo(unsigned int w) { return bf2f((unsigned short)(w & 0xffff)); }
__device__ __forceinline__ float bfhi(unsigned int w) { return bf2f((unsigned short)(w >> 16)); }
__device__ __forceinline__ unsigned int pk2(float lo, float hi) {
    return (unsigned int)f2bf(lo) | ((unsigned int)f2bf(hi) << 16);
}

// ---------- CSR build (bucket-hierarchical: NO per-edge global atomics) ----------

// Per-block LDS histogram over dst buckets; one global atomic per (block, bucket).
__global__ __launch_bounds__(256) void k_bhist(const int* __restrict__ ei, int E, int N,
                                               int* __restrict__ bcnt) {
    __shared__ int hist[1024];
    int K = ((N + 255) >> BSH);
    int t = threadIdx.x;
    long long cb = (long long)blockIdx.x * ACHUNK;
    for (int i = t; i < K; i += 256) hist[i] = 0;
    __syncthreads();
#pragma unroll
    for (int i = 0; i < 16; ++i) {
        long long e = cb + t + (long long)i * 256;
        if (e < E) {
            int ss = ei[e];
            int dd = ei[E + e];
            if ((unsigned)ss < (unsigned)N && (unsigned)dd < (unsigned)N)
                atomicAdd(&hist[dd >> BSH], 1);
        }
    }
    __syncthreads();
    for (int i = t; i < K; i += 256) {
        int h = hist[i];
        if (h) atomicAdd(&bcnt[i], h);
    }
}

// Single-block exclusive scan of bcnt[0..K) -> bstart, gcur  (requires K <= 1024).
__global__ __launch_bounds__(1024) void k_scanb(const int* __restrict__ bcnt, int K,
                                                int* __restrict__ bstart,
                                                int* __restrict__ gcur) {
    __shared__ int tmp[1024];
    int t = threadIdx.x;
    int v = (t < K) ? bcnt[t] : 0;
    tmp[t] = v;
    __syncthreads();
    for (int off = 1; off < 1024; off <<= 1) {
        int a = (t >= off) ? tmp[t - off] : 0;
        __syncthreads();
        tmp[t] += a;
        __syncthreads();
    }
    if (t < K) { int s = tmp[t] - v; bstart[t] = s; gcur[t] = s; }
}

// Pass A: bucket edges by dst>>8 into pairs[], line-coalesced appends.
__global__ __launch_bounds__(256) void k_passA(const int* __restrict__ ei, int E, int N,
                                               int* __restrict__ gcur,
                                               int2* __restrict__ pairs) {
    __shared__ int hist[1024];
    __shared__ int base[1024];
    int K = ((N + 255) >> BSH);
    int t = threadIdx.x;
    long long cb = (long long)blockIdx.x * ACHUNK;
    for (int i = t; i < K; i += 256) hist[i] = 0;
    __syncthreads();
    int sv[16], dv[16];
#pragma unroll
    for (int i = 0; i < 16; ++i) {
        sv[i] = -1; dv[i] = 0;
        long long e = cb + t + (long long)i * 256;
        if (e < E) {
            int ss = ei[e];
            int dd = ei[E + e];
            if ((unsigned)ss < (unsigned)N && (unsigned)dd < (unsigned)N) {
                sv[i] = ss; dv[i] = dd;
            }
        }
    }
#pragma unroll
    for (int i = 0; i < 16; ++i)
        if (sv[i] >= 0) atomicAdd(&hist[dv[i] >> BSH], 1);
    __syncthreads();
    for (int i = t; i < K; i += 256) {
        int h = hist[i];
        base[i] = h ? atomicAdd(&gcur[i], h) : 0;
    }
    __syncthreads();
    for (int i = t; i < K; i += 256) hist[i] = 0;
    __syncthreads();
#pragma unroll
    for (int i = 0; i < 16; ++i) {
        if (sv[i] >= 0) {
            int b = dv[i] >> BSH;
            int off = atomicAdd(&hist[b], 1);
            pairs[base[b] + off] = make_int2(sv[i], dv[i]);
        }
    }
}

// Pass B2: per bucket -- derive per-node degrees in LDS (no global atomics),
// in-LDS exclusive scan -> row starts, write deg/cursor, scatter pairs->adj,
// and append deg<MAXDEG node ids to the compact flagged list.
__global__ __launch_bounds__(256) void k_passB2(const int2* __restrict__ pairs,
                                                const int* __restrict__ bstart,
                                                const int* __restrict__ gcur,
                                                int* __restrict__ deg,
                                                int* __restrict__ cursor,
                                                int* __restrict__ adj,
                                                int* __restrict__ nflag,
                                                int* __restrict__ flist, int N) {
    __shared__ int cnt[256];
    __shared__ int scn[256];
    __shared__ int cur[256];
    __shared__ int fids[256];
    __shared__ int fcnt, fbase;
    int b = blockIdx.x;
    int lo = b << BSH;
    int t = threadIdx.x;
    int nvalid = min(256, N - lo);
    cnt[t] = 0;
    if (t == 0) fcnt = 0;
    int pstart = bstart[b];
    int pend = gcur[b];
    __syncthreads();
    for (int i = pstart + t; i < pend; i += 256)
        atomicAdd(&cnt[pairs[i].y - lo], 1);
    __syncthreads();
    int v = cnt[t];
    scn[t] = v;
    __syncthreads();
    for (int off = 1; off < 256; off <<= 1) {
        int a = (t >= off) ? scn[t - off] : 0;
        __syncthreads();
        scn[t] += a;
        __syncthreads();
    }
    int rowstart = pstart + scn[t] - v;
    cur[t] = rowstart;
    if (t < nvalid) {
        deg[lo + t] = v;
        cursor[lo + t] = rowstart + v;    // cursor = row END
        if (v < MAXDEG) { int p = atomicAdd(&fcnt, 1); fids[p] = lo + t; }
    }
    __syncthreads();
    if (t == 0 && fcnt > 0) fbase = atomicAdd(nflag, fcnt);
    __syncthreads();
    if (t < fcnt) flist[fbase + t] = fids[t];
    for (int i = pstart + t; i < pend; i += 256) {
        int2 pr = pairs[i];
        int pos = atomicAdd(&cur[pr.y - lo], 1);
        adj[pos] = pr.x;
    }
}

// ---------- prepack bucket-10 weights as bf16, B-operand layout [n][k] ----------
// wcat1: [64 n][128 k]; n<32 -> W1[10][k][n], else Wr1[10][k][n-32]
// wcat2: [128 n][32 k]; n<64 -> W2[10][k][n], else Wr2[10][k][n-64]
__global__ __launch_bounds__(256) void k_prepack(const float* __restrict__ W1,
                                                 const float* __restrict__ Wr1,
                                                 const float* __restrict__ W2,
                                                 const float* __restrict__ Wr2,
                                                 unsigned short* __restrict__ wcat1,
                                                 unsigned short* __restrict__ wcat2) {
    int t = threadIdx.x;
    const float* W1b  = W1  + (size_t)MAXDEG * FIN * FHID;
    const float* Wr1b = Wr1 + (size_t)MAXDEG * FIN * FHID;
    const float* W2b  = W2  + (size_t)MAXDEG * FHID * FOUT;
    const float* Wr2b = Wr2 + (size_t)MAXDEG * FHID * FOUT;
    for (int i = 0; i < 32; ++i) {
        int idx = i * 256 + t;            // 8192
        int n = idx >> 7, k = idx & 127;
        float v = (n < 32) ? W1b[k * FHID + n] : Wr1b[k * FHID + (n - 32)];
        wcat1[idx] = f2bf(v);
    }
    for (int i = 0; i < 16; ++i) {
        int idx = i * 256 + t;            // 4096
        int n = idx >> 5, k = idx & 31;
        float v = (n < 64) ? W2b[k * FOUT + n] : Wr2b[k * FOUT + (n - 64)];
        wcat2[idx] = f2bf(v);
    }
}

// ---------- pre1 (MFMA): [z10 | r1] = x @ [W1[10] | Wr1[10]] + [0 | b1[10]] ----------
__global__ __launch_bounds__(256) void k_pre1m(const float* __restrict__ x,
                                               const unsigned short* __restrict__ wcat1,
                                               const float* __restrict__ b1,
                                               unsigned short* __restrict__ z10,
                                               unsigned short* __restrict__ r1, int N) {
    __shared__ __align__(16) unsigned short xt[64 * XPAD];
    __shared__ __align__(16) unsigned short wt[64 * XPAD];
    int t = threadIdx.x;
    int row0 = blockIdx.x * 64;
    {   // stage Wcat1 (8192 bf16 = 1024 uint4)
        const uint4* src = (const uint4*)wcat1;
#pragma unroll
        for (int i = 0; i < 4; ++i) {
            int idx = i * 256 + t;
            uint4 v = src[idx];
            int n = idx >> 4;
            int k = (idx & 15) * 8;
            *(uint4*)(wt + n * XPAD + k) = v;
        }
    }
    {   // stage x rows -> bf16
        int r = t >> 2;
        int c0 = (t & 3) * 32;
        int cr = min(row0 + r, N - 1);
        const float4* xs = (const float4*)(x + (size_t)cr * FIN + c0);
        unsigned short* dst = xt + r * XPAD + c0;
#pragma unroll
        for (int i = 0; i < 8; ++i) {
            float4 v = xs[i];
            ushort4 b;
            b.x = f2bf(v.x); b.y = f2bf(v.y); b.z = f2bf(v.z); b.w = f2bf(v.w);
            *(ushort4*)(dst + i * 4) = b;
        }
    }
    __syncthreads();
    int w = t >> 6, lane = t & 63;
    int m = lane & 15, quad = lane >> 4;
    const unsigned short* arow = xt + (w * 16 + m) * XPAD + quad * 8;
    short8 af[4];
#pragma unroll
    for (int kt = 0; kt < 4; ++kt) af[kt] = *(const short8*)(arow + kt * 32);
    f32x4 acc[4];
#pragma unroll
    for (int ct = 0; ct < 4; ++ct) acc[ct] = (f32x4){0.f, 0.f, 0.f, 0.f};
#pragma unroll
    for (int ct = 0; ct < 4; ++ct) {
        const unsigned short* brow = wt + (ct * 16 + m) * XPAD + quad * 8;
#pragma unroll
        for (int kt = 0; kt < 4; ++kt) {
            short8 bfr = *(const short8*)(brow + kt * 32);
            acc[ct] = __builtin_amdgcn_mfma_f32_16x16x32_bf16(af[kt], bfr, acc[ct], 0, 0, 0);
        }
    }
    int rbase = row0 + w * 16 + quad * 4;
#pragma unroll
    for (int ct = 0; ct < 4; ++ct) {
        float bias = (ct >= 2) ? b1[MAXDEG * FHID + (ct - 2) * 16 + m] : 0.f;
#pragma unroll
        for (int rg = 0; rg < 4; ++rg) {
            int n = rbase + rg;
            if (n < N) {
                float v = acc[ct][rg];
                if (ct < 2) z10[(size_t)n * FHID + ct * 16 + m] = f2bf(v);
                else        r1[(size_t)n * FHID + (ct - 2) * 16 + m] = f2bf(v + bias);
            }
        }
    }
}

// fixup (compacted, wave-per-node): full layer1 output via true-bucket weights.
__global__ __launch_bounds__(256) void k_fix1c(const float* __restrict__ x,
                                               const int* __restrict__ deg,
                                               const int* __restrict__ cursor,
                                               const int* __restrict__ adj,
                                               const float* __restrict__ W1,
                                               const float* __restrict__ b1,
                                               const float* __restrict__ Wr1,
                                               const int* __restrict__ nflag,
                                               const int* __restrict__ flist,
                                               unsigned short* __restrict__ out1, int N) {
    int wid = (blockIdx.x * 256 + threadIdx.x) >> 6;
    int nw = gridDim.x * 4;
    int lane = threadIdx.x & 63;
    int u = lane >> 5, o = lane & 31;
    int fcnt = *nflag;
    for (int i = wid; i < fcnt; i += nw) {
        int n = flist[i];
        int d = deg[n];
        // root term: Wr1[d]^T x_n  (split-K across halves u)
        const float* Wr = Wr1 + (size_t)d * (FIN * FHID) + o;
        const float4* xr = (const float4*)(x + (size_t)n * FIN);
        float racc = 0.f;
        for (int c = u * 16; c < u * 16 + 16; ++c) {
            float4 xv = xr[c];
            racc += xv.x * Wr[(c * 4 + 0) * FHID] + xv.y * Wr[(c * 4 + 1) * FHID]
                  + xv.z * Wr[(c * 4 + 2) * FHID] + xv.w * Wr[(c * 4 + 3) * FHID];
        }
        racc += __shfl_xor(racc, 32);
        // neighbor aggregate: h = sum x_j  (feats lane*2, lane*2+1 per lane)
        int e1 = cursor[n];
        int e0 = e1 - d;
        float2 h = make_float2(0.f, 0.f);
        for (int k = e0; k < e1; ++k) {
            int s = adj[k];
            float2 v = *(const float2*)(x + (size_t)s * FIN + lane * 2);
            h.x += v.x; h.y += v.y;
        }
        // transform: W1[d]^T h  (split-K across halves u)
        const float* Wp = W1 + (size_t)d * (FIN * FHID) + o;
        float acc = 0.f;
        for (int f = u * 64; f < u * 64 + 64; ++f) {
            float hf = __shfl((f & 1) ? h.y : h.x, f >> 1);
            acc += hf * Wp[f * FHID];
        }
        acc += __shfl_xor(acc, 32);
        if (lane < 32) {
            float rv = racc + b1[d * FHID + o];
            out1[(size_t)n * FHID + o] = f2bf(fmaxf(acc + rv, 0.f));
        }
    }
}

// ---------- 16-lane/edge gather core: lane = (edge e = lane>>4, feat-pair f2 = lane&15) ----------
// Returns per-lane partial sums a0,a1 for feats 2*f2, 2*f2+1 (pre-reduce).
__device__ __forceinline__ void gather16(const unsigned short* __restrict__ rows,
                                         const int* __restrict__ adj,
                                         int e0, int e1, int cnt, int lane,
                                         float& a0, float& a1) {
    int e = lane >> 4, f2 = lane & 15;
    int sidx = adj[min(e0 + lane, e1 - 1)];
    const unsigned short* rb = rows + f2 * 2;
    int nch = (cnt + 15) >> 4;
    for (int c = 0; c < nch; ++c) {
        int i0 = c * 16 + e;
        int i1 = i0 + 4, i2 = i0 + 8, i3 = i0 + 12;
        int s0 = __shfl(sidx, min(i0, cnt - 1));
        int s1 = __shfl(sidx, min(i1, cnt - 1));
        int s2 = __shfl(sidx, min(i2, cnt - 1));
        int s3 = __shfl(sidx, min(i3, cnt - 1));
        unsigned int w0 = *(const unsigned int*)(rb + (size_t)s0 * FHID);
        unsigned int w1 = *(const unsigned int*)(rb + (size_t)s1 * FHID);
        unsigned int w2 = *(const unsigned int*)(rb + (size_t)s2 * FHID);
        unsigned int w3 = *(const unsigned int*)(rb + (size_t)s3 * FHID);
        float c0 = (i0 < cnt) ? 1.f : 0.f;
        float c1 = (i1 < cnt) ? 1.f : 0.f;
        float c2 = (i2 < cnt) ? 1.f : 0.f;
        float c3 = (i3 < cnt) ? 1.f : 0.f;
        a0 = fmaf(c0, bflo(w0), a0); a1 = fmaf(c0, bfhi(w0), a1);
        a0 = fmaf(c1, bflo(w1), a0); a1 = fmaf(c1, bfhi(w1), a1);
        a0 = fmaf(c2, bflo(w2), a0); a1 = fmaf(c2, bfhi(w2), a1);
        a0 = fmaf(c3, bflo(w3), a0); a1 = fmaf(c3, bfhi(w3), a1);
    }
    for (int k = e0 + 64 + e; k < e1; k += 4) {    // rare tail (deg>64)
        int s = adj[k];
        unsigned int w = *(const unsigned int*)(rb + (size_t)s * FHID);
        a0 += bflo(w); a1 += bfhi(w);
    }
}

// ---------- layer1 fast path (deg>=10): gather z10, out1 = relu(h + r1) ----------
__global__ __launch_bounds__(256) void k_layer1b(const unsigned short* __restrict__ z10,
                                                 const unsigned short* __restrict__ r1,
                                                 const int* __restrict__ deg,
                                                 const int* __restrict__ cursor,
                                                 const int* __restrict__ adj,
                                                 unsigned short* __restrict__ out1, int N) {
    int wave = (int)(((long long)blockIdx.x * 256 + threadIdx.x) >> 6);
    if (wave >= N) return;
    int n = wave;
    int lane = threadIdx.x & 63;
    int dg = deg[n];
    if (dg < MAXDEG) return;           // handled by k_fix1c
    int e1 = cursor[n];
    int e0 = e1 - dg;
    float a0 = 0.f, a1 = 0.f;
    gather16(z10, adj, e0, e1, min(dg, 64), lane, a0, a1);
    a0 += __shfl_xor(a0, 16); a1 += __shfl_xor(a1, 16);
    a0 += __shfl_xor(a0, 32); a1 += __shfl_xor(a1, 32);
    if (lane < 16) {
        int f2 = lane;
        unsigned int rv = *(const unsigned int*)(r1 + (size_t)n * FHID + f2 * 2);
        unsigned int w = pk2(fmaxf(a0 + bflo(rv), 0.f), fmaxf(a1 + bfhi(rv), 0.f));
        *(unsigned int*)(out1 + (size_t)n * FHID + f2 * 2) = w;
    }
}

// ---------- layer2 gather (ALL nodes): g[n] = sum_{j in N(n)} y_j  (f32) ----------
__global__ __launch_bounds__(256) void k_layer2g(const unsigned short* __restrict__ y,
                                                 const int* __restrict__ deg,
                                                 const int* __restrict__ cursor,
                                                 const int* __restrict__ adj,
                                                 float* __restrict__ g, int N) {
    int wave = (int)(((long long)blockIdx.x * 256 + threadIdx.x) >> 6);
    if (wave >= N) return;
    int n = wave;
    int lane = threadIdx.x & 63;
    int dg = deg[n];
    float a0 = 0.f, a1 = 0.f;
    if (dg > 0) {
        int e1 = cursor[n];
        int e0 = e1 - dg;
        gather16(y, adj, e0, e1, min(dg, 64), lane, a0, a1);
        a0 += __shfl_xor(a0, 16); a1 += __shfl_xor(a1, 16);
        a0 += __shfl_xor(a0, 32); a1 += __shfl_xor(a1, 32);
    }
    if (lane < 16) {
        *(float2*)(g + (size_t)n * FHID + lane * 2) = make_float2(a0, a1);
    }
}

// ---------- post2 (MFMA, dense): out = g @ W2[10] + y @ Wr2[10] + b2[10] ----------
__global__ __launch_bounds__(256) void k_post2m(const float* __restrict__ g,
                                                const unsigned short* __restrict__ y,
                                                const unsigned short* __restrict__ wcat2,
                                                const float* __restrict__ b2,
                                                float* __restrict__ out, int N) {
    __shared__ __align__(16) unsigned short gt[64 * YPAD];
    __shared__ __align__(16) unsigned short yt[64 * YPAD];
    __shared__ __align__(16) unsigned short wt[128 * YPAD];
    int t = threadIdx.x;
    int row0 = blockIdx.x * 64;
    {   // stage wcat2 (4096 bf16 = 512 uint4): [128 n][32 k]
        const uint4* src = (const uint4*)wcat2;
#pragma unroll
        for (int i = 0; i < 2; ++i) {
            int idx = i * 256 + t;
            uint4 v = src[idx];
            int nn = idx >> 2;
            int k = (idx & 3) * 8;
            *(uint4*)(wt + nn * YPAD + k) = v;
        }
    }
    {   // stage g rows (f32 -> bf16) and y rows (bf16)
        int r = t >> 2, c0 = (t & 3) * 8;
        int rn = min(row0 + r, N - 1);
        const float4* gs = (const float4*)(g + (size_t)rn * FHID + c0);
        float4 v0 = gs[0], v1 = gs[1];
        ushort4 p0, p1;
        p0.x = f2bf(v0.x); p0.y = f2bf(v0.y); p0.z = f2bf(v0.z); p0.w = f2bf(v0.w);
        p1.x = f2bf(v1.x); p1.y = f2bf(v1.y); p1.z = f2bf(v1.z); p1.w = f2bf(v1.w);
        *(ushort4*)(gt + r * YPAD + c0) = p0;
        *(ushort4*)(gt + r * YPAD + c0 + 4) = p1;
        uint4 vy = *(const uint4*)(y + (size_t)rn * FHID + c0);
        *(uint4*)(yt + r * YPAD + c0) = vy;
    }
    __syncthreads();
    int w = t >> 6, lane = t & 63;
    int m = lane & 15, quad = lane >> 4;
    short8 ag = *(const short8*)(gt + (w * 16 + m) * YPAD + quad * 8);
    short8 ay = *(const short8*)(yt + (w * 16 + m) * YPAD + quad * 8);
    int rbase = row0 + w * 16 + quad * 4;
#pragma unroll
    for (int ct = 0; ct < 4; ++ct) {
        short8 bw = *(const short8*)(wt + (ct * 16 + m) * YPAD + quad * 8);
        short8 br = *(const short8*)(wt + ((64 + ct * 16) + m) * YPAD + quad * 8);
        f32x4 acc = (f32x4){0.f, 0.f, 0.f, 0.f};
        acc = __builtin_amdgcn_mfma_f32_16x16x32_bf16(ag, bw, acc, 0, 0, 0);
        acc = __builtin_amdgcn_mfma_f32_16x16x32_bf16(ay, br, acc, 0, 0, 0);
        int o = ct * 16 + m;
        float bias = b2[MAXDEG * FOUT + o];
#pragma unroll
        for (int rg = 0; rg < 4; ++rg) {
            int nn = rbase + rg;
            if (nn < N) out[(size_t)nn * FOUT + o] = acc[rg] + bias;
        }
    }
}

// fixup (compacted, wave-per-node): exact out rows via true-bucket W2[d]/Wr2[d].
__global__ __launch_bounds__(256) void k_fix2c(const float* __restrict__ g,
                                               const unsigned short* __restrict__ y,
                                               const int* __restrict__ deg,
                                               const float* __restrict__ b2,
                                               const float* __restrict__ W2,
                                               const float* __restrict__ Wr2,
                                               const int* __restrict__ nflag,
                                               const int* __restrict__ flist,
                                               float* __restrict__ out, int N) {
    int wid = (blockIdx.x * 256 + threadIdx.x) >> 6;
    int nw = gridDim.x * 4;
    int lane = threadIdx.x & 63;
    int fcnt = *nflag;
    for (int i = wid; i < fcnt; i += nw) {
        int n = flist[i];
        int d = deg[n];
        const float* W2p  = W2  + (size_t)d * (FHID * FOUT) + lane;
        const float* Wr2p = Wr2 + (size_t)d * (FHID * FOUT) + lane;
        float2 gv = *(const float2*)(g + (size_t)n * FHID + (lane & 15) * 2);
        unsigned int yw = *(const unsigned int*)(y + (size_t)n * FHID + (lane & 15) * 2);
        float acc = b2[d * FOUT + lane];
#pragma unroll
        for (int q = 0; q < 16; ++q) {
            float g0 = __shfl(gv.x, q);
            float g1 = __shfl(gv.y, q);
            unsigned int yq = __shfl(yw, q);
            acc += g0 * W2p[(2 * q) * FOUT] + g1 * W2p[(2 * q + 1) * FOUT]
                 + bflo(yq) * Wr2p[(2 * q) * FOUT] + bfhi(yq) * Wr2p[(2 * q + 1) * FOUT];
        }
        out[(size_t)n * FOUT + lane] = acc;
    }
}

extern "C" void kernel_launch(void* const* d_in, const int* in_sizes, int n_in,
                              void* d_out, int out_size, void* d_ws, size_t ws_size,
                              hipStream_t stream) {
    const float* x   = (const float*)d_in[0];
    const int*   ei  = (const int*)d_in[1];   // int32, [2, E] flat
    const float* W1  = (const float*)d_in[2];
    const float* b1  = (const float*)d_in[3];
    const float* Wr1 = (const float*)d_in[4];
    const float* W2  = (const float*)d_in[5];
    const float* b2  = (const float*)d_in[6];
    const float* Wr2 = (const float*)d_in[7];

    int N = in_sizes[0] / FIN;
    int E = in_sizes[1] / 2;
    int K  = (N + 255) >> BSH;   // dst buckets

    char* ws = (char*)d_ws;
    size_t off = 0;
    auto alloc = [&](size_t bytes) {
        void* ptr = ws + off;
        off += (bytes + 511) / 512 * 512;
        return ptr;
    };
    int* deg              = (int*)alloc((size_t)N * sizeof(int));
    int* cursor           = (int*)alloc((size_t)N * sizeof(int));
    int* bcnt             = (int*)alloc((size_t)(K + 1) * sizeof(int));  // +1: nflag counter
    int* nflag            = bcnt + K;
    int* bstart           = (int*)alloc((size_t)K * sizeof(int));
    int* gcur             = (int*)alloc((size_t)K * sizeof(int));
    int* flist            = (int*)alloc((size_t)N * sizeof(int));
    int* adj              = (int*)alloc((size_t)E * sizeof(int));
    unsigned short* z10   = (unsigned short*)alloc((size_t)N * FHID * 2);
    unsigned short* r1    = (unsigned short*)alloc((size_t)N * FHID * 2);
    unsigned short* out1  = (unsigned short*)alloc((size_t)N * FHID * 2);
    // pairs (E*8B) and g (N*FHID*4B) share one region: pairs dead after k_passB2,
    // g first written by k_layer2g which runs later.
    size_t pairsB = (size_t)E * sizeof(int2);
    size_t gB     = (size_t)N * FHID * sizeof(float);
    void* shared_region   = alloc(pairsB > gB ? pairsB : gB);
    float* g              = (float*)shared_region;
    int2* pairs           = (int2*)shared_region;
    unsigned short* wcat1 = (unsigned short*)alloc(64 * 128 * 2);
    unsigned short* wcat2 = (unsigned short*)alloc(128 * 32 * 2);

    float* out = (float*)d_out;

    hipMemsetAsync(bcnt, 0, (size_t)(K + 1) * sizeof(int), stream);

    int nwgA = (E + ACHUNK - 1) / ACHUNK;
    k_prepack<<<1, 256, 0, stream>>>(W1, Wr1, W2, Wr2, wcat1, wcat2);
    k_bhist<<<nwgA, 256, 0, stream>>>(ei, E, N, bcnt);
    k_scanb<<<1, 1024, 0, stream>>>(bcnt, K, bstart, gcur);
    k_passA<<<nwgA, 256, 0, stream>>>(ei, E, N, gcur, pairs);
    k_passB2<<<K, 256, 0, stream>>>(pairs, bstart, gcur, deg, cursor, adj, nflag, flist, N);

    int nb64 = (N + 63) / 64;     // MFMA kernels: 64 nodes per block
    int nb_node = (N + 3) / 4;    // gather kernels: wave per node
    int nbfix = 1024;             // fixups: wave-per-flagged-node, grid-stride

    k_pre1m<<<nb64, 256, 0, stream>>>(x, wcat1, b1, z10, r1, N);
    k_fix1c<<<nbfix, 256, 0, stream>>>(x, deg, cursor, adj, W1, b1, Wr1, nflag, flist, out1, N);
    k_layer1b<<<nb_node, 256, 0, stream>>>(z10, r1, deg, cursor, adj, out1, N);
    k_layer2g<<<nb_node, 256, 0, stream>>>(out1, deg, cursor, adj, g, N);
    k_post2m<<<nb64, 256, 0, stream>>>(g, out1, wcat2, b2, out, N);
    k_fix2c<<<nbfix, 256, 0, stream>>>(g, out1, deg, b2, W2, Wr2, nflag, flist, out, N);
}

// Round 7
// 287.461 us; speedup vs baseline: 3.6370x; 1.0233x over previous
//
#include <hip/hip_runtime.h>

#define FIN 128
#define FHID 32
#define FOUT 64
#define MAXDEG 10
#define BSH 8              // dst bucket = dst >> 8 (256 dsts per bucket)
#define ACHUNK 4096        // edges per pass-A workgroup (16 per thread)
#define XPAD 136           // LDS row stride (bf16) for 128-k tiles
#define YPAD 40            // LDS row stride (bf16) for 32-k tiles: 80B, 16B-aligned
#define SRCBITS 20         // packed pair: src in bits 0..19 (requires N < 2^20), dst&255 in 20..27

typedef __attribute__((ext_vector_type(8))) short short8;
typedef __attribute__((ext_vector_type(4))) float f32x4;

// edge_index arrives as int32: layout [2, E] flat: src = ei[e], dst = ei[E + e].

__device__ __forceinline__ float bf2f(unsigned short u) {
    union { unsigned int i; float f; } c; c.i = ((unsigned int)u) << 16; return c.f;
}
__device__ __forceinline__ unsigned short f2bf(float f) {
    union { float f; unsigned int i; } c; c.f = f;
    unsigned int r = c.i + 0x7FFF + ((c.i >> 16) & 1);   // round-nearest-even
    return (unsigned short)(r >> 16);
}
__device__ __forceinline__ float bflo(unsigned int w) { return bf2f((unsigned short)(w & 0xffff)); }
__device__ __forceinline__ float bfhi(unsigned int w) { return bf2f((unsigned short)(w >> 16)); }
__device__ __forceinline__ unsigned int pk2(float lo, float hi) {
    return (unsigned int)f2bf(lo) | ((unsigned int)f2bf(hi) << 16);
}

// ---------- CSR build (bucket-hierarchical: NO per-edge global atomics) ----------

// Per-block LDS histogram over dst buckets; one global atomic per (block, bucket).
// Block 0 additionally prepacks the bucket-10 weights (hidden under other blocks).
__global__ __launch_bounds__(256) void k_bhistp(const int* __restrict__ ei, int E, int N,
                                                int* __restrict__ bcnt,
                                                const float* __restrict__ W1,
                                                const float* __restrict__ Wr1,
                                                const float* __restrict__ W2,
                                                const float* __restrict__ Wr2,
                                                unsigned short* __restrict__ wcat1,
                                                unsigned short* __restrict__ wcat2) {
    __shared__ int hist[1024];
    int K = ((N + 255) >> BSH);
    int t = threadIdx.x;
    long long cb = (long long)blockIdx.x * ACHUNK;
    for (int i = t; i < K; i += 256) hist[i] = 0;
    __syncthreads();
#pragma unroll
    for (int i = 0; i < 16; ++i) {
        long long e = cb + t + (long long)i * 256;
        if (e < E) {
            int ss = ei[e];
            int dd = ei[E + e];
            if ((unsigned)ss < (unsigned)N && (unsigned)dd < (unsigned)N)
                atomicAdd(&hist[dd >> BSH], 1);
        }
    }
    __syncthreads();
    for (int i = t; i < K; i += 256) {
        int h = hist[i];
        if (h) atomicAdd(&bcnt[i], h);
    }
    if (blockIdx.x == 0) {   // prepack: wcat1 [64n][128k], wcat2 [128n][32k]
        const float* W1b  = W1  + (size_t)MAXDEG * FIN * FHID;
        const float* Wr1b = Wr1 + (size_t)MAXDEG * FIN * FHID;
        const float* W2b  = W2  + (size_t)MAXDEG * FHID * FOUT;
        const float* Wr2b = Wr2 + (size_t)MAXDEG * FHID * FOUT;
        for (int i = 0; i < 32; ++i) {
            int idx = i * 256 + t;            // 8192
            int n = idx >> 7, k = idx & 127;
            float v = (n < 32) ? W1b[k * FHID + n] : Wr1b[k * FHID + (n - 32)];
            wcat1[idx] = f2bf(v);
        }
        for (int i = 0; i < 16; ++i) {
            int idx = i * 256 + t;            // 4096
            int n = idx >> 5, k = idx & 31;
            float v = (n < 64) ? W2b[k * FOUT + n] : Wr2b[k * FOUT + (n - 64)];
            wcat2[idx] = f2bf(v);
        }
    }
}

// Single-block exclusive scan of bcnt[0..K) -> bstart, gcur  (requires K <= 1024).
__global__ __launch_bounds__(1024) void k_scanb(const int* __restrict__ bcnt, int K,
                                                int* __restrict__ bstart,
                                                int* __restrict__ gcur) {
    __shared__ int tmp[1024];
    int t = threadIdx.x;
    int v = (t < K) ? bcnt[t] : 0;
    tmp[t] = v;
    __syncthreads();
    for (int off = 1; off < 1024; off <<= 1) {
        int a = (t >= off) ? tmp[t - off] : 0;
        __syncthreads();
        tmp[t] += a;
        __syncthreads();
    }
    if (t < K) { int s = tmp[t] - v; bstart[t] = s; gcur[t] = s; }
}

// Pass A: bucket edges by dst>>8 into packed pairs[], line-coalesced appends.
__global__ __launch_bounds__(256) void k_passA(const int* __restrict__ ei, int E, int N,
                                               int* __restrict__ gcur,
                                               unsigned int* __restrict__ pairs) {
    __shared__ int hist[1024];
    __shared__ int base[1024];
    int K = ((N + 255) >> BSH);
    int t = threadIdx.x;
    long long cb = (long long)blockIdx.x * ACHUNK;
    for (int i = t; i < K; i += 256) hist[i] = 0;
    __syncthreads();
    int sv[16], dv[16];
#pragma unroll
    for (int i = 0; i < 16; ++i) {
        sv[i] = -1; dv[i] = 0;
        long long e = cb + t + (long long)i * 256;
        if (e < E) {
            int ss = ei[e];
            int dd = ei[E + e];
            if ((unsigned)ss < (unsigned)N && (unsigned)dd < (unsigned)N) {
                sv[i] = ss; dv[i] = dd;
            }
        }
    }
#pragma unroll
    for (int i = 0; i < 16; ++i)
        if (sv[i] >= 0) atomicAdd(&hist[dv[i] >> BSH], 1);
    __syncthreads();
    for (int i = t; i < K; i += 256) {
        int h = hist[i];
        base[i] = h ? atomicAdd(&gcur[i], h) : 0;
    }
    __syncthreads();
    for (int i = t; i < K; i += 256) hist[i] = 0;
    __syncthreads();
#pragma unroll
    for (int i = 0; i < 16; ++i) {
        if (sv[i] >= 0) {
            int b = dv[i] >> BSH;
            int off = atomicAdd(&hist[b], 1);
            pairs[base[b] + off] = (unsigned int)sv[i] | ((unsigned int)(dv[i] & 255) << SRCBITS);
        }
    }
}

// Pass B2: per bucket -- derive per-node degrees in LDS (no global atomics),
// in-LDS exclusive scan -> row starts, write deg/cursor, scatter pairs->adj,
// and append deg<MAXDEG node ids to the compact flagged list.
__global__ __launch_bounds__(256) void k_passB2(const unsigned int* __restrict__ pairs,
                                                const int* __restrict__ bstart,
                                                const int* __restrict__ gcur,
                                                int* __restrict__ deg,
                                                int* __restrict__ cursor,
                                                int* __restrict__ adj,
                                                int* __restrict__ nflag,
                                                int* __restrict__ flist, int N) {
    __shared__ int cnt[256];
    __shared__ int scn[256];
    __shared__ int cur[256];
    __shared__ int fids[256];
    __shared__ int fcnt, fbase;
    int b = blockIdx.x;
    int lo = b << BSH;
    int t = threadIdx.x;
    int nvalid = min(256, N - lo);
    cnt[t] = 0;
    if (t == 0) fcnt = 0;
    int pstart = bstart[b];
    int pend = gcur[b];
    __syncthreads();
    for (int i = pstart + t; i < pend; i += 256)
        atomicAdd(&cnt[pairs[i] >> SRCBITS], 1);
    __syncthreads();
    int v = cnt[t];
    scn[t] = v;
    __syncthreads();
    for (int off = 1; off < 256; off <<= 1) {
        int a = (t >= off) ? scn[t - off] : 0;
        __syncthreads();
        scn[t] += a;
        __syncthreads();
    }
    int rowstart = pstart + scn[t] - v;
    cur[t] = rowstart;
    if (t < nvalid) {
        deg[lo + t] = v;
        cursor[lo + t] = rowstart + v;    // cursor = row END
        if (v < MAXDEG) { int p = atomicAdd(&fcnt, 1); fids[p] = lo + t; }
    }
    __syncthreads();
    if (t == 0 && fcnt > 0) fbase = atomicAdd(nflag, fcnt);
    __syncthreads();
    if (t < fcnt) flist[fbase + t] = fids[t];
    for (int i = pstart + t; i < pend; i += 256) {
        unsigned int pr = pairs[i];
        int pos = atomicAdd(&cur[pr >> SRCBITS], 1);
        adj[pos] = (int)(pr & ((1u << SRCBITS) - 1));
    }
}

// ---------- pre1 (MFMA): [z10 | r1] = x @ [W1[10] | Wr1[10]] + [0 | b1[10]] ----------
__global__ __launch_bounds__(256) void k_pre1m(const float* __restrict__ x,
                                               const unsigned short* __restrict__ wcat1,
                                               const float* __restrict__ b1,
                                               unsigned short* __restrict__ z10,
                                               unsigned short* __restrict__ r1, int N) {
    __shared__ __align__(16) unsigned short xt[64 * XPAD];
    __shared__ __align__(16) unsigned short wt[64 * XPAD];
    int t = threadIdx.x;
    int row0 = blockIdx.x * 64;
    {   // stage Wcat1 (8192 bf16 = 1024 uint4)
        const uint4* src = (const uint4*)wcat1;
#pragma unroll
        for (int i = 0; i < 4; ++i) {
            int idx = i * 256 + t;
            uint4 v = src[idx];
            int n = idx >> 4;
            int k = (idx & 15) * 8;
            *(uint4*)(wt + n * XPAD + k) = v;
        }
    }
    {   // stage x rows -> bf16
        int r = t >> 2;
        int c0 = (t & 3) * 32;
        int cr = min(row0 + r, N - 1);
        const float4* xs = (const float4*)(x + (size_t)cr * FIN + c0);
        unsigned short* dst = xt + r * XPAD + c0;
#pragma unroll
        for (int i = 0; i < 8; ++i) {
            float4 v = xs[i];
            ushort4 b;
            b.x = f2bf(v.x); b.y = f2bf(v.y); b.z = f2bf(v.z); b.w = f2bf(v.w);
            *(ushort4*)(dst + i * 4) = b;
        }
    }
    __syncthreads();
    int w = t >> 6, lane = t & 63;
    int m = lane & 15, quad = lane >> 4;
    const unsigned short* arow = xt + (w * 16 + m) * XPAD + quad * 8;
    short8 af[4];
#pragma unroll
    for (int kt = 0; kt < 4; ++kt) af[kt] = *(const short8*)(arow + kt * 32);
    f32x4 acc[4];
#pragma unroll
    for (int ct = 0; ct < 4; ++ct) acc[ct] = (f32x4){0.f, 0.f, 0.f, 0.f};
#pragma unroll
    for (int ct = 0; ct < 4; ++ct) {
        const unsigned short* brow = wt + (ct * 16 + m) * XPAD + quad * 8;
#pragma unroll
        for (int kt = 0; kt < 4; ++kt) {
            short8 bfr = *(const short8*)(brow + kt * 32);
            acc[ct] = __builtin_amdgcn_mfma_f32_16x16x32_bf16(af[kt], bfr, acc[ct], 0, 0, 0);
        }
    }
    int rbase = row0 + w * 16 + quad * 4;
#pragma unroll
    for (int ct = 0; ct < 4; ++ct) {
        float bias = (ct >= 2) ? b1[MAXDEG * FHID + (ct - 2) * 16 + m] : 0.f;
#pragma unroll
        for (int rg = 0; rg < 4; ++rg) {
            int n = rbase + rg;
            if (n < N) {
                float v = acc[ct][rg];
                if (ct < 2) z10[(size_t)n * FHID + ct * 16 + m] = f2bf(v);
                else        r1[(size_t)n * FHID + (ct - 2) * 16 + m] = f2bf(v + bias);
            }
        }
    }
}

// ---------- 16-lane/edge gather core: lane = (edge e = lane>>4, feat-pair f2 = lane&15) ----------
// Full chunks skip clamp/select; partial chunk clamps+scales. Pre-reduce partials in a0,a1.
__device__ __forceinline__ void gather16(const unsigned short* __restrict__ rows,
                                         const int* __restrict__ adj,
                                         int e0, int e1, int cnt, int lane,
                                         float& a0, float& a1) {
    int e = lane >> 4, f2 = lane & 15;
    int sidx = adj[min(e0 + lane, e1 - 1)];
    const unsigned short* rb = rows + f2 * 2;
    int nfull = cnt >> 4;
    for (int c = 0; c < nfull; ++c) {
        int i0 = c * 16 + e;
        int s0 = __shfl(sidx, i0);
        int s1 = __shfl(sidx, i0 + 4);
        int s2 = __shfl(sidx, i0 + 8);
        int s3 = __shfl(sidx, i0 + 12);
        unsigned int w0 = *(const unsigned int*)(rb + (size_t)s0 * FHID);
        unsigned int w1 = *(const unsigned int*)(rb + (size_t)s1 * FHID);
        unsigned int w2 = *(const unsigned int*)(rb + (size_t)s2 * FHID);
        unsigned int w3 = *(const unsigned int*)(rb + (size_t)s3 * FHID);
        a0 += bflo(w0); a1 += bfhi(w0);
        a0 += bflo(w1); a1 += bfhi(w1);
        a0 += bflo(w2); a1 += bfhi(w2);
        a0 += bflo(w3); a1 += bfhi(w3);
    }
    if (cnt & 15) {
        int i0 = nfull * 16 + e;
        int i1 = i0 + 4, i2 = i0 + 8, i3 = i0 + 12;
        int s0 = __shfl(sidx, min(i0, cnt - 1));
        int s1 = __shfl(sidx, min(i1, cnt - 1));
        int s2 = __shfl(sidx, min(i2, cnt - 1));
        int s3 = __shfl(sidx, min(i3, cnt - 1));
        unsigned int w0 = *(const unsigned int*)(rb + (size_t)s0 * FHID);
        unsigned int w1 = *(const unsigned int*)(rb + (size_t)s1 * FHID);
        unsigned int w2 = *(const unsigned int*)(rb + (size_t)s2 * FHID);
        unsigned int w3 = *(const unsigned int*)(rb + (size_t)s3 * FHID);
        float c0 = (i0 < cnt) ? 1.f : 0.f;
        float c1 = (i1 < cnt) ? 1.f : 0.f;
        float c2 = (i2 < cnt) ? 1.f : 0.f;
        float c3 = (i3 < cnt) ? 1.f : 0.f;
        a0 = fmaf(c0, bflo(w0), a0); a1 = fmaf(c0, bfhi(w0), a1);
        a0 = fmaf(c1, bflo(w1), a0); a1 = fmaf(c1, bfhi(w1), a1);
        a0 = fmaf(c2, bflo(w2), a0); a1 = fmaf(c2, bfhi(w2), a1);
        a0 = fmaf(c3, bflo(w3), a0); a1 = fmaf(c3, bfhi(w3), a1);
    }
    for (int k = e0 + 64 + e; k < e1; k += 4) {    // rare tail (deg>64)
        int s = adj[k];
        unsigned int w = *(const unsigned int*)(rb + (size_t)s * FHID);
        a0 += bflo(w); a1 += bfhi(w);
    }
}

// ---------- layer1 fused: fast blocks gather z10 (deg>=10); tail blocks do deg<10 fixup ----------
__global__ __launch_bounds__(256) void k_layer1x(const unsigned short* __restrict__ z10,
                                                 const unsigned short* __restrict__ r1,
                                                 const int* __restrict__ deg,
                                                 const int* __restrict__ cursor,
                                                 const int* __restrict__ adj,
                                                 const float* __restrict__ x,
                                                 const float* __restrict__ W1,
                                                 const float* __restrict__ b1,
                                                 const float* __restrict__ Wr1,
                                                 const int* __restrict__ nflag,
                                                 const int* __restrict__ flist,
                                                 unsigned short* __restrict__ out1,
                                                 int N, int nbFast) {
    int t = threadIdx.x;
    int lane = t & 63;
    if ((int)blockIdx.x < nbFast) {
        int n = blockIdx.x * 4 + (t >> 6);
        if (n >= N) return;
        int dg = deg[n];
        if (dg < MAXDEG) return;           // handled by fix blocks
        int e1 = cursor[n];
        int e0 = e1 - dg;
        float a0 = 0.f, a1 = 0.f;
        gather16(z10, adj, e0, e1, min(dg, 64), lane, a0, a1);
        a0 += __shfl_xor(a0, 16); a1 += __shfl_xor(a1, 16);
        a0 += __shfl_xor(a0, 32); a1 += __shfl_xor(a1, 32);
        if (lane < 16) {
            unsigned int rv = *(const unsigned int*)(r1 + (size_t)n * FHID + lane * 2);
            unsigned int w = pk2(fmaxf(a0 + bflo(rv), 0.f), fmaxf(a1 + bfhi(rv), 0.f));
            *(unsigned int*)(out1 + (size_t)n * FHID + lane * 2) = w;
        }
    } else {
        int wid = ((blockIdx.x - nbFast) * 256 + t) >> 6;
        int nw = (gridDim.x - nbFast) * 4;
        int u = lane >> 5, o = lane & 31;
        int fcnt = *nflag;
        for (int i = wid; i < fcnt; i += nw) {
            int n = flist[i];
            int d = deg[n];
            // root term: Wr1[d]^T x_n  (split-K across halves u)
            const float* Wr = Wr1 + (size_t)d * (FIN * FHID) + o;
            const float4* xr = (const float4*)(x + (size_t)n * FIN);
            float racc = 0.f;
            for (int c = u * 16; c < u * 16 + 16; ++c) {
                float4 xv = xr[c];
                racc += xv.x * Wr[(c * 4 + 0) * FHID] + xv.y * Wr[(c * 4 + 1) * FHID]
                      + xv.z * Wr[(c * 4 + 2) * FHID] + xv.w * Wr[(c * 4 + 3) * FHID];
            }
            racc += __shfl_xor(racc, 32);
            // neighbor aggregate: h = sum x_j  (feats lane*2, lane*2+1 per lane)
            int e1 = cursor[n];
            int e0 = e1 - d;
            float2 h = make_float2(0.f, 0.f);
            for (int k = e0; k < e1; ++k) {
                int s = adj[k];
                float2 v = *(const float2*)(x + (size_t)s * FIN + lane * 2);
                h.x += v.x; h.y += v.y;
            }
            // transform: W1[d]^T h  (split-K across halves u)
            const float* Wp = W1 + (size_t)d * (FIN * FHID) + o;
            float acc = 0.f;
            for (int f = u * 64; f < u * 64 + 64; ++f) {
                float hf = __shfl((f & 1) ? h.y : h.x, f >> 1);
                acc += hf * Wp[f * FHID];
            }
            acc += __shfl_xor(acc, 32);
            if (lane < 32) {
                float rv = racc + b1[d * FHID + o];
                out1[(size_t)n * FHID + o] = f2bf(fmaxf(acc + rv, 0.f));
            }
        }
    }
}

// ---------- layer2 gather (ALL nodes): g[n] = sum_{j in N(n)} y_j  (f32) ----------
__global__ __launch_bounds__(256) void k_layer2g(const unsigned short* __restrict__ y,
                                                 const int* __restrict__ deg,
                                                 const int* __restrict__ cursor,
                                                 const int* __restrict__ adj,
                                                 float* __restrict__ g, int N) {
    int wave = (int)(((long long)blockIdx.x * 256 + threadIdx.x) >> 6);
    if (wave >= N) return;
    int n = wave;
    int lane = threadIdx.x & 63;
    int dg = deg[n];
    float a0 = 0.f, a1 = 0.f;
    if (dg > 0) {
        int e1 = cursor[n];
        int e0 = e1 - dg;
        gather16(y, adj, e0, e1, min(dg, 64), lane, a0, a1);
        a0 += __shfl_xor(a0, 16); a1 += __shfl_xor(a1, 16);
        a0 += __shfl_xor(a0, 32); a1 += __shfl_xor(a1, 32);
    }
    if (lane < 16) {
        *(float2*)(g + (size_t)n * FHID + lane * 2) = make_float2(a0, a1);
    }
}

// ---------- post2 fused: fast blocks MFMA (skip flagged rows); tail blocks exact deg<10 fixup ----------
__global__ __launch_bounds__(256) void k_post2x(const float* __restrict__ g,
                                                const unsigned short* __restrict__ y,
                                                const unsigned short* __restrict__ wcat2,
                                                const float* __restrict__ b2,
                                                const int* __restrict__ deg,
                                                const int* __restrict__ cursor,
                                                const int* __restrict__ adj,
                                                const float* __restrict__ W2full,
                                                const float* __restrict__ Wr2full,
                                                const int* __restrict__ nflag,
                                                const int* __restrict__ flist,
                                                float* __restrict__ out,
                                                int N, int nbFast) {
    int t = threadIdx.x;
    if ((int)blockIdx.x < nbFast) {
        __shared__ __align__(16) unsigned short gt[64 * YPAD];
        __shared__ __align__(16) unsigned short yt[64 * YPAD];
        __shared__ __align__(16) unsigned short wt[128 * YPAD];
        __shared__ unsigned char flg[64];
        int row0 = blockIdx.x * 64;
        {   // stage wcat2 (4096 bf16 = 512 uint4): [128 n][32 k]
            const uint4* src = (const uint4*)wcat2;
#pragma unroll
            for (int i = 0; i < 2; ++i) {
                int idx = i * 256 + t;
                uint4 v = src[idx];
                int nn = idx >> 2;
                int k = (idx & 3) * 8;
                *(uint4*)(wt + nn * YPAD + k) = v;
            }
        }
        if (t < 64) {
            int rn = row0 + t;
            flg[t] = (rn < N) ? (unsigned char)(deg[rn] < MAXDEG) : (unsigned char)1;
        }
        {   // stage g rows (f32 -> bf16) and y rows (bf16)
            int r = t >> 2, c0 = (t & 3) * 8;
            int rn = min(row0 + r, N - 1);
            const float4* gs = (const float4*)(g + (size_t)rn * FHID + c0);
            float4 v0 = gs[0], v1 = gs[1];
            ushort4 p0, p1;
            p0.x = f2bf(v0.x); p0.y = f2bf(v0.y); p0.z = f2bf(v0.z); p0.w = f2bf(v0.w);
            p1.x = f2bf(v1.x); p1.y = f2bf(v1.y); p1.z = f2bf(v1.z); p1.w = f2bf(v1.w);
            *(ushort4*)(gt + r * YPAD + c0) = p0;
            *(ushort4*)(gt + r * YPAD + c0 + 4) = p1;
            uint4 vy = *(const uint4*)(y + (size_t)rn * FHID + c0);
            *(uint4*)(yt + r * YPAD + c0) = vy;
        }
        __syncthreads();
        int w = t >> 6, lane = t & 63;
        int m = lane & 15, quad = lane >> 4;
        short8 ag = *(const short8*)(gt + (w * 16 + m) * YPAD + quad * 8);
        short8 ay = *(const short8*)(yt + (w * 16 + m) * YPAD + quad * 8);
        int rbase = w * 16 + quad * 4;   // block-local row
#pragma unroll
        for (int ct = 0; ct < 4; ++ct) {
            short8 bw = *(const short8*)(wt + (ct * 16 + m) * YPAD + quad * 8);
            short8 br = *(const short8*)(wt + ((64 + ct * 16) + m) * YPAD + quad * 8);
            f32x4 acc = (f32x4){0.f, 0.f, 0.f, 0.f};
            acc = __builtin_amdgcn_mfma_f32_16x16x32_bf16(ag, bw, acc, 0, 0, 0);
            acc = __builtin_amdgcn_mfma_f32_16x16x32_bf16(ay, br, acc, 0, 0, 0);
            int o = ct * 16 + m;
            float bias = b2[MAXDEG * FOUT + o];
#pragma unroll
            for (int rg = 0; rg < 4; ++rg) {
                int rl = rbase + rg;
                int nn = row0 + rl;
                if (nn < N && !flg[rl]) out[(size_t)nn * FOUT + o] = acc[rg] + bias;
            }
        }
    } else {
        int wid = ((blockIdx.x - nbFast) * 256 + t) >> 6;
        int nw = (gridDim.x - nbFast) * 4;
        int lane = t & 63;
        int fcnt = *nflag;
        for (int i = wid; i < fcnt; i += nw) {
            int n = flist[i];
            int d = deg[n];
            float a0 = 0.f, a1 = 0.f;
            if (d > 0) {
                int e1 = cursor[n];
                gather16(y, adj, e1 - d, e1, d, lane, a0, a1);
                a0 += __shfl_xor(a0, 16); a1 += __shfl_xor(a1, 16);
                a0 += __shfl_xor(a0, 32); a1 += __shfl_xor(a1, 32);
            }
            const float* W2p  = W2full  + (size_t)d * (FHID * FOUT) + lane;
            const float* Wr2p = Wr2full + (size_t)d * (FHID * FOUT) + lane;
            unsigned int yw = *(const unsigned int*)(y + (size_t)n * FHID + (lane & 15) * 2);
            float acc = b2[d * FOUT + lane];
#pragma unroll
            for (int q = 0; q < 16; ++q) {
                float g0 = __shfl(a0, q);
                float g1 = __shfl(a1, q);
                unsigned int yq = __shfl(yw, q);
                acc += g0 * W2p[(2 * q) * FOUT] + g1 * W2p[(2 * q + 1) * FOUT]
                     + bflo(yq) * Wr2p[(2 * q) * FOUT] + bfhi(yq) * Wr2p[(2 * q + 1) * FOUT];
            }
            out[(size_t)n * FOUT + lane] = acc;
        }
    }
}

extern "C" void kernel_launch(void* const* d_in, const int* in_sizes, int n_in,
                              void* d_out, int out_size, void* d_ws, size_t ws_size,
                              hipStream_t stream) {
    const float* x   = (const float*)d_in[0];
    const int*   ei  = (const int*)d_in[1];   // int32, [2, E] flat
    const float* W1  = (const float*)d_in[2];
    const float* b1  = (const float*)d_in[3];
    const float* Wr1 = (const float*)d_in[4];
    const float* W2  = (const float*)d_in[5];
    const float* b2  = (const float*)d_in[6];
    const float* Wr2 = (const float*)d_in[7];

    int N = in_sizes[0] / FIN;
    int E = in_sizes[1] / 2;
    int K  = (N + 255) >> BSH;   // dst buckets

    char* ws = (char*)d_ws;
    size_t off = 0;
    auto alloc = [&](size_t bytes) {
        void* ptr = ws + off;
        off += (bytes + 511) / 512 * 512;
        return ptr;
    };
    int* deg              = (int*)alloc((size_t)N * sizeof(int));
    int* cursor           = (int*)alloc((size_t)N * sizeof(int));
    int* bcnt             = (int*)alloc((size_t)(K + 1) * sizeof(int));  // +1: nflag counter
    int* nflag            = bcnt + K;
    int* bstart           = (int*)alloc((size_t)K * sizeof(int));
    int* gcur             = (int*)alloc((size_t)K * sizeof(int));
    int* flist            = (int*)alloc((size_t)N * sizeof(int));
    int* adj              = (int*)alloc((size_t)E * sizeof(int));
    unsigned short* z10   = (unsigned short*)alloc((size_t)N * FHID * 2);
    unsigned short* r1    = (unsigned short*)alloc((size_t)N * FHID * 2);
    unsigned short* out1  = (unsigned short*)alloc((size_t)N * FHID * 2);
    // packed pairs (E*4B) and g (N*FHID*4B) share one region: pairs dead after k_passB2,
    // g first written by k_layer2g which runs later.
    size_t pairsB = (size_t)E * sizeof(unsigned int);
    size_t gB     = (size_t)N * FHID * sizeof(float);
    void* shared_region   = alloc(pairsB > gB ? pairsB : gB);
    float* g              = (float*)shared_region;
    unsigned int* pairs   = (unsigned int*)shared_region;
    unsigned short* wcat1 = (unsigned short*)alloc(64 * 128 * 2);
    unsigned short* wcat2 = (unsigned short*)alloc(128 * 32 * 2);

    float* out = (float*)d_out;

    (void)hipMemsetAsync(bcnt, 0, (size_t)(K + 1) * sizeof(int), stream);

    int nwgA = (E + ACHUNK - 1) / ACHUNK;
    k_bhistp<<<nwgA, 256, 0, stream>>>(ei, E, N, bcnt, W1, Wr1, W2, Wr2, wcat1, wcat2);
    k_scanb<<<1, 1024, 0, stream>>>(bcnt, K, bstart, gcur);
    k_passA<<<nwgA, 256, 0, stream>>>(ei, E, N, gcur, pairs);
    k_passB2<<<K, 256, 0, stream>>>(pairs, bstart, gcur, deg, cursor, adj, nflag, flist, N);

    int nb64 = (N + 63) / 64;     // MFMA kernels: 64 nodes per block
    int nb_node = (N + 3) / 4;    // gather kernels: wave per node
    const int FIXB = 512;         // fixup tail blocks (wave-per-flagged-node, grid-stride)

    k_pre1m<<<nb64, 256, 0, stream>>>(x, wcat1, b1, z10, r1, N);
    k_layer1x<<<nb_node + FIXB, 256, 0, stream>>>(z10, r1, deg, cursor, adj,
                                                  x, W1, b1, Wr1, nflag, flist, out1,
                                                  N, nb_node);
    k_layer2g<<<nb_node, 256, 0, stream>>>(out1, deg, cursor, adj, g, N);
    k_post2x<<<nb64 + FIXB, 256, 0, stream>>>(g, out1, wcat2, b2, deg, cursor, adj,
                                              W2, Wr2, nflag, flist, out, N, nb64);
}

// Round 8
// 271.530 us; speedup vs baseline: 3.8504x; 1.0587x over previous
//
#include <hip/hip_runtime.h>

#define FIN 128
#define FHID 32
#define FOUT 64
#define MAXDEG 10
#define BSH 8              // dst bucket = dst >> 8 (256 dsts per bucket)
#define ACHUNK 4096        // edges per pass-A workgroup (16 per thread)
#define XPAD 136           // LDS row stride (bf16) for 128-k tiles
#define YPAD 40            // LDS row stride (bf16) for 32-k tiles: 80B, 16B-aligned
#define SRCBITS 20         // packed pair: src in bits 0..19 (requires N < 2^20), dst&255 in 20..27

typedef __attribute__((ext_vector_type(8))) short short8;
typedef __attribute__((ext_vector_type(4))) float f32x4;

// edge_index arrives as int32: layout [2, E] flat: src = ei[e], dst = ei[E + e].

__device__ __forceinline__ float bf2f(unsigned short u) {
    union { unsigned int i; float f; } c; c.i = ((unsigned int)u) << 16; return c.f;
}
__device__ __forceinline__ unsigned short f2bf(float f) {
    union { float f; unsigned int i; } c; c.f = f;
    unsigned int r = c.i + 0x7FFF + ((c.i >> 16) & 1);   // round-nearest-even
    return (unsigned short)(r >> 16);
}
__device__ __forceinline__ float bflo(unsigned int w) { return bf2f((unsigned short)(w & 0xffff)); }
__device__ __forceinline__ float bfhi(unsigned int w) { return bf2f((unsigned short)(w >> 16)); }
__device__ __forceinline__ unsigned int pk2(float lo, float hi) {
    return (unsigned int)f2bf(lo) | ((unsigned int)f2bf(hi) << 16);
}

// ---------- CSR build (bucket-hierarchical: NO per-edge global atomics) ----------

// Per-block LDS histogram over dst buckets; one global atomic per (block, bucket).
// Block 0 additionally prepacks the bucket-10 weights (hidden under other blocks).
__global__ __launch_bounds__(256) void k_bhistp(const int* __restrict__ ei, int E, int N,
                                                int* __restrict__ bcnt,
                                                const float* __restrict__ W1,
                                                const float* __restrict__ Wr1,
                                                const float* __restrict__ W2,
                                                const float* __restrict__ Wr2,
                                                unsigned short* __restrict__ wcat1,
                                                unsigned short* __restrict__ wcat2) {
    __shared__ int hist[1024];
    int K = ((N + 255) >> BSH);
    int t = threadIdx.x;
    long long cb = (long long)blockIdx.x * ACHUNK;
    for (int i = t; i < K; i += 256) hist[i] = 0;
    __syncthreads();
#pragma unroll
    for (int i = 0; i < 16; ++i) {
        long long e = cb + t + (long long)i * 256;
        if (e < E) {
            int ss = ei[e];
            int dd = ei[E + e];
            if ((unsigned)ss < (unsigned)N && (unsigned)dd < (unsigned)N)
                atomicAdd(&hist[dd >> BSH], 1);
        }
    }
    __syncthreads();
    for (int i = t; i < K; i += 256) {
        int h = hist[i];
        if (h) atomicAdd(&bcnt[i], h);
    }
    if (blockIdx.x == 0) {   // prepack: wcat1 [64n][128k], wcat2 [128n][32k]
        const float* W1b  = W1  + (size_t)MAXDEG * FIN * FHID;
        const float* Wr1b = Wr1 + (size_t)MAXDEG * FIN * FHID;
        const float* W2b  = W2  + (size_t)MAXDEG * FHID * FOUT;
        const float* Wr2b = Wr2 + (size_t)MAXDEG * FHID * FOUT;
        for (int i = 0; i < 32; ++i) {
            int idx = i * 256 + t;            // 8192
            int n = idx >> 7, k = idx & 127;
            float v = (n < 32) ? W1b[k * FHID + n] : Wr1b[k * FHID + (n - 32)];
            wcat1[idx] = f2bf(v);
        }
        for (int i = 0; i < 16; ++i) {
            int idx = i * 256 + t;            // 4096
            int n = idx >> 5, k = idx & 31;
            float v = (n < 64) ? W2b[k * FOUT + n] : Wr2b[k * FOUT + (n - 64)];
            wcat2[idx] = f2bf(v);
        }
    }
}

// Single-block exclusive scan of bcnt[0..K) -> bstart, gcur  (requires K <= 1024).
__global__ __launch_bounds__(1024) void k_scanb(const int* __restrict__ bcnt, int K,
                                                int* __restrict__ bstart,
                                                int* __restrict__ gcur) {
    __shared__ int tmp[1024];
    int t = threadIdx.x;
    int v = (t < K) ? bcnt[t] : 0;
    tmp[t] = v;
    __syncthreads();
    for (int off = 1; off < 1024; off <<= 1) {
        int a = (t >= off) ? tmp[t - off] : 0;
        __syncthreads();
        tmp[t] += a;
        __syncthreads();
    }
    if (t < K) { int s = tmp[t] - v; bstart[t] = s; gcur[t] = s; }
}

// Pass A: bucket edges by dst>>8 into packed pairs[], line-coalesced appends.
__global__ __launch_bounds__(256) void k_passA(const int* __restrict__ ei, int E, int N,
                                               int* __restrict__ gcur,
                                               unsigned int* __restrict__ pairs) {
    __shared__ int hist[1024];
    __shared__ int base[1024];
    int K = ((N + 255) >> BSH);
    int t = threadIdx.x;
    long long cb = (long long)blockIdx.x * ACHUNK;
    for (int i = t; i < K; i += 256) hist[i] = 0;
    __syncthreads();
    int sv[16], dv[16];
#pragma unroll
    for (int i = 0; i < 16; ++i) {
        sv[i] = -1; dv[i] = 0;
        long long e = cb + t + (long long)i * 256;
        if (e < E) {
            int ss = ei[e];
            int dd = ei[E + e];
            if ((unsigned)ss < (unsigned)N && (unsigned)dd < (unsigned)N) {
                sv[i] = ss; dv[i] = dd;
            }
        }
    }
#pragma unroll
    for (int i = 0; i < 16; ++i)
        if (sv[i] >= 0) atomicAdd(&hist[dv[i] >> BSH], 1);
    __syncthreads();
    for (int i = t; i < K; i += 256) {
        int h = hist[i];
        base[i] = h ? atomicAdd(&gcur[i], h) : 0;
    }
    __syncthreads();
    for (int i = t; i < K; i += 256) hist[i] = 0;
    __syncthreads();
#pragma unroll
    for (int i = 0; i < 16; ++i) {
        if (sv[i] >= 0) {
            int b = dv[i] >> BSH;
            int off = atomicAdd(&hist[b], 1);
            pairs[base[b] + off] = (unsigned int)sv[i] | ((unsigned int)(dv[i] & 255) << SRCBITS);
        }
    }
}

// Pass B2: per bucket -- derive per-node degrees in LDS (no global atomics),
// in-LDS exclusive scan -> row starts, write deg/cursor, scatter pairs->adj,
// and append deg<MAXDEG node ids to the compact flagged list.
__global__ __launch_bounds__(256) void k_passB2(const unsigned int* __restrict__ pairs,
                                                const int* __restrict__ bstart,
                                                const int* __restrict__ gcur,
                                                int* __restrict__ deg,
                                                int* __restrict__ cursor,
                                                int* __restrict__ adj,
                                                int* __restrict__ nflag,
                                                int* __restrict__ flist, int N) {
    __shared__ int cnt[256];
    __shared__ int scn[256];
    __shared__ int cur[256];
    __shared__ int fids[256];
    __shared__ int fcnt, fbase;
    int b = blockIdx.x;
    int lo = b << BSH;
    int t = threadIdx.x;
    int nvalid = min(256, N - lo);
    cnt[t] = 0;
    if (t == 0) fcnt = 0;
    int pstart = bstart[b];
    int pend = gcur[b];
    __syncthreads();
    for (int i = pstart + t; i < pend; i += 256)
        atomicAdd(&cnt[pairs[i] >> SRCBITS], 1);
    __syncthreads();
    int v = cnt[t];
    scn[t] = v;
    __syncthreads();
    for (int off = 1; off < 256; off <<= 1) {
        int a = (t >= off) ? scn[t - off] : 0;
        __syncthreads();
        scn[t] += a;
        __syncthreads();
    }
    int rowstart = pstart + scn[t] - v;
    cur[t] = rowstart;
    if (t < nvalid) {
        deg[lo + t] = v;
        cursor[lo + t] = rowstart + v;    // cursor = row END
        if (v < MAXDEG) { int p = atomicAdd(&fcnt, 1); fids[p] = lo + t; }
    }
    __syncthreads();
    if (t == 0 && fcnt > 0) fbase = atomicAdd(nflag, fcnt);
    __syncthreads();
    if (t < fcnt) flist[fbase + t] = fids[t];
    for (int i = pstart + t; i < pend; i += 256) {
        unsigned int pr = pairs[i];
        int pos = atomicAdd(&cur[pr >> SRCBITS], 1);
        adj[pos] = (int)(pr & ((1u << SRCBITS) - 1));
    }
}

// ---------- pre1 (MFMA): [z10 | r1] = x @ [W1[10] | Wr1[10]] + [0 | b1[10]] ----------
__global__ __launch_bounds__(256) void k_pre1m(const float* __restrict__ x,
                                               const unsigned short* __restrict__ wcat1,
                                               const float* __restrict__ b1,
                                               unsigned short* __restrict__ z10,
                                               unsigned short* __restrict__ r1, int N) {
    __shared__ __align__(16) unsigned short xt[64 * XPAD];
    __shared__ __align__(16) unsigned short wt[64 * XPAD];
    int t = threadIdx.x;
    int row0 = blockIdx.x * 64;
    {   // stage Wcat1 (8192 bf16 = 1024 uint4)
        const uint4* src = (const uint4*)wcat1;
#pragma unroll
        for (int i = 0; i < 4; ++i) {
            int idx = i * 256 + t;
            uint4 v = src[idx];
            int n = idx >> 4;
            int k = (idx & 15) * 8;
            *(uint4*)(wt + n * XPAD + k) = v;
        }
    }
    {   // stage x rows -> bf16
        int r = t >> 2;
        int c0 = (t & 3) * 32;
        int cr = min(row0 + r, N - 1);
        const float4* xs = (const float4*)(x + (size_t)cr * FIN + c0);
        unsigned short* dst = xt + r * XPAD + c0;
#pragma unroll
        for (int i = 0; i < 8; ++i) {
            float4 v = xs[i];
            ushort4 b;
            b.x = f2bf(v.x); b.y = f2bf(v.y); b.z = f2bf(v.z); b.w = f2bf(v.w);
            *(ushort4*)(dst + i * 4) = b;
        }
    }
    __syncthreads();
    int w = t >> 6, lane = t & 63;
    int m = lane & 15, quad = lane >> 4;
    const unsigned short* arow = xt + (w * 16 + m) * XPAD + quad * 8;
    short8 af[4];
#pragma unroll
    for (int kt = 0; kt < 4; ++kt) af[kt] = *(const short8*)(arow + kt * 32);
    f32x4 acc[4];
#pragma unroll
    for (int ct = 0; ct < 4; ++ct) acc[ct] = (f32x4){0.f, 0.f, 0.f, 0.f};
#pragma unroll
    for (int ct = 0; ct < 4; ++ct) {
        const unsigned short* brow = wt + (ct * 16 + m) * XPAD + quad * 8;
#pragma unroll
        for (int kt = 0; kt < 4; ++kt) {
            short8 bfr = *(const short8*)(brow + kt * 32);
            acc[ct] = __builtin_amdgcn_mfma_f32_16x16x32_bf16(af[kt], bfr, acc[ct], 0, 0, 0);
        }
    }
    int rbase = row0 + w * 16 + quad * 4;
#pragma unroll
    for (int ct = 0; ct < 4; ++ct) {
        float bias = (ct >= 2) ? b1[MAXDEG * FHID + (ct - 2) * 16 + m] : 0.f;
#pragma unroll
        for (int rg = 0; rg < 4; ++rg) {
            int n = rbase + rg;
            if (n < N) {
                float v = acc[ct][rg];
                if (ct < 2) z10[(size_t)n * FHID + ct * 16 + m] = f2bf(v);
                else        r1[(size_t)n * FHID + (ct - 2) * 16 + m] = f2bf(v + bias);
            }
        }
    }
}

// ---------- single-node 16-lane/edge gather (fixup paths) ----------
__device__ __forceinline__ void gather16(const unsigned short* __restrict__ rows,
                                         const int* __restrict__ adj,
                                         int e0, int e1, int cnt, int lane,
                                         float& a0, float& a1) {
    int e = lane >> 4, f2 = lane & 15;
    int sidx = adj[min(e0 + lane, e1 - 1)];
    const unsigned short* rb = rows + f2 * 2;
    int nfull = cnt >> 4;
    for (int c = 0; c < nfull; ++c) {
        int i0 = c * 16 + e;
        int s0 = __shfl(sidx, i0);
        int s1 = __shfl(sidx, i0 + 4);
        int s2 = __shfl(sidx, i0 + 8);
        int s3 = __shfl(sidx, i0 + 12);
        unsigned int w0 = *(const unsigned int*)(rb + (size_t)s0 * FHID);
        unsigned int w1 = *(const unsigned int*)(rb + (size_t)s1 * FHID);
        unsigned int w2 = *(const unsigned int*)(rb + (size_t)s2 * FHID);
        unsigned int w3 = *(const unsigned int*)(rb + (size_t)s3 * FHID);
        a0 += bflo(w0); a1 += bfhi(w0);
        a0 += bflo(w1); a1 += bfhi(w1);
        a0 += bflo(w2); a1 += bfhi(w2);
        a0 += bflo(w3); a1 += bfhi(w3);
    }
    if (cnt & 15) {
        int i0 = nfull * 16 + e;
        int i1 = i0 + 4, i2 = i0 + 8, i3 = i0 + 12;
        int s0 = __shfl(sidx, min(i0, cnt - 1));
        int s1 = __shfl(sidx, min(i1, cnt - 1));
        int s2 = __shfl(sidx, min(i2, cnt - 1));
        int s3 = __shfl(sidx, min(i3, cnt - 1));
        unsigned int w0 = *(const unsigned int*)(rb + (size_t)s0 * FHID);
        unsigned int w1 = *(const unsigned int*)(rb + (size_t)s1 * FHID);
        unsigned int w2 = *(const unsigned int*)(rb + (size_t)s2 * FHID);
        unsigned int w3 = *(const unsigned int*)(rb + (size_t)s3 * FHID);
        float c0 = (i0 < cnt) ? 1.f : 0.f;
        float c1 = (i1 < cnt) ? 1.f : 0.f;
        float c2 = (i2 < cnt) ? 1.f : 0.f;
        float c3 = (i3 < cnt) ? 1.f : 0.f;
        a0 = fmaf(c0, bflo(w0), a0); a1 = fmaf(c0, bfhi(w0), a1);
        a0 = fmaf(c1, bflo(w1), a0); a1 = fmaf(c1, bfhi(w1), a1);
        a0 = fmaf(c2, bflo(w2), a0); a1 = fmaf(c2, bfhi(w2), a1);
        a0 = fmaf(c3, bflo(w3), a0); a1 = fmaf(c3, bfhi(w3), a1);
    }
    for (int k = e0 + 64 + e; k < e1; k += 4) {    // rare tail (deg>64)
        int s = adj[k];
        unsigned int w = *(const unsigned int*)(rb + (size_t)s * FHID);
        a0 += bflo(w); a1 += bfhi(w);
    }
}

// ---------- 2-node interleaved gather: 8 loads in flight per chunk ----------
// Node A: accumulate into a0,a1; node B into b0,b1. cntX==0 disables node X (loads
// degenerate to a single broadcast address, contributions masked to 0).
__device__ __forceinline__ void gather16x2(const unsigned short* __restrict__ rows,
                                           const int* __restrict__ adj,
                                           int e0a, int e1a, int cntA,
                                           int e0b, int e1b, int cntB, int lane,
                                           float& a0, float& a1, float& b0, float& b1) {
    int e = lane >> 4, f2 = lane & 15;
    const unsigned short* rb = rows + f2 * 2;
    int cA = max(cntA - 1, 0);
    int cB = max(cntB - 1, 0);
    int sA = adj[e0a + min(lane, cA)];
    int sB = adj[e0b + min(lane, cB)];
    int nch = (max(cntA, cntB) + 15) >> 4;
    for (int c = 0; c < nch; ++c) {
        int i0 = c * 16 + e;
        int i1 = i0 + 4, i2 = i0 + 8, i3 = i0 + 12;
        int as0 = __shfl(sA, min(i0, cA));
        int as1 = __shfl(sA, min(i1, cA));
        int as2 = __shfl(sA, min(i2, cA));
        int as3 = __shfl(sA, min(i3, cA));
        int bs0 = __shfl(sB, min(i0, cB));
        int bs1 = __shfl(sB, min(i1, cB));
        int bs2 = __shfl(sB, min(i2, cB));
        int bs3 = __shfl(sB, min(i3, cB));
        unsigned int aw0 = *(const unsigned int*)(rb + (size_t)as0 * FHID);
        unsigned int aw1 = *(const unsigned int*)(rb + (size_t)as1 * FHID);
        unsigned int aw2 = *(const unsigned int*)(rb + (size_t)as2 * FHID);
        unsigned int aw3 = *(const unsigned int*)(rb + (size_t)as3 * FHID);
        unsigned int bw0 = *(const unsigned int*)(rb + (size_t)bs0 * FHID);
        unsigned int bw1 = *(const unsigned int*)(rb + (size_t)bs1 * FHID);
        unsigned int bw2 = *(const unsigned int*)(rb + (size_t)bs2 * FHID);
        unsigned int bw3 = *(const unsigned int*)(rb + (size_t)bs3 * FHID);
        float ac0 = (i0 < cntA) ? 1.f : 0.f;
        float ac1 = (i1 < cntA) ? 1.f : 0.f;
        float ac2 = (i2 < cntA) ? 1.f : 0.f;
        float ac3 = (i3 < cntA) ? 1.f : 0.f;
        float bc0 = (i0 < cntB) ? 1.f : 0.f;
        float bc1 = (i1 < cntB) ? 1.f : 0.f;
        float bc2 = (i2 < cntB) ? 1.f : 0.f;
        float bc3 = (i3 < cntB) ? 1.f : 0.f;
        a0 = fmaf(ac0, bflo(aw0), a0); a1 = fmaf(ac0, bfhi(aw0), a1);
        a0 = fmaf(ac1, bflo(aw1), a0); a1 = fmaf(ac1, bfhi(aw1), a1);
        a0 = fmaf(ac2, bflo(aw2), a0); a1 = fmaf(ac2, bfhi(aw2), a1);
        a0 = fmaf(ac3, bflo(aw3), a0); a1 = fmaf(ac3, bfhi(aw3), a1);
        b0 = fmaf(bc0, bflo(bw0), b0); b1 = fmaf(bc0, bfhi(bw0), b1);
        b0 = fmaf(bc1, bflo(bw1), b0); b1 = fmaf(bc1, bfhi(bw1), b1);
        b0 = fmaf(bc2, bflo(bw2), b0); b1 = fmaf(bc2, bfhi(bw2), b1);
        b0 = fmaf(bc3, bflo(bw3), b0); b1 = fmaf(bc3, bfhi(bw3), b1);
    }
    for (int k = e0a + 64 + e; k < e1a; k += 4) {    // rare tail (deg>64)
        int s = adj[k];
        unsigned int w = *(const unsigned int*)(rb + (size_t)s * FHID);
        a0 += bflo(w); a1 += bfhi(w);
    }
    for (int k = e0b + 64 + e; k < e1b; k += 4) {
        int s = adj[k];
        unsigned int w = *(const unsigned int*)(rb + (size_t)s * FHID);
        b0 += bflo(w); b1 += bfhi(w);
    }
}

// ---------- layer1 fused: fast blocks gather z10 (2 nodes/wave); tail blocks deg<10 fixup ----------
__global__ __launch_bounds__(256) void k_layer1x(const unsigned short* __restrict__ z10,
                                                 const unsigned short* __restrict__ r1,
                                                 const int* __restrict__ deg,
                                                 const int* __restrict__ cursor,
                                                 const int* __restrict__ adj,
                                                 const float* __restrict__ x,
                                                 const float* __restrict__ W1,
                                                 const float* __restrict__ b1,
                                                 const float* __restrict__ Wr1,
                                                 const int* __restrict__ nflag,
                                                 const int* __restrict__ flist,
                                                 unsigned short* __restrict__ out1,
                                                 int N, int nbFast) {
    int t = threadIdx.x;
    int lane = t & 63;
    if ((int)blockIdx.x < nbFast) {
        int n0 = blockIdx.x * 8 + (t >> 6) * 2;
        int n1 = n0 + 1;
        bool ok0 = (n0 < N), ok1 = (n1 < N);
        int dg0 = ok0 ? deg[n0] : 0;
        int dg1 = ok1 ? deg[n1] : 0;
        ok0 = ok0 && (dg0 >= MAXDEG);          // deg<10 handled by fix blocks
        ok1 = ok1 && (dg1 >= MAXDEG);
        if (!ok0 && !ok1) return;
        int e1a = ok0 ? cursor[n0] : 0;
        int e1b = ok1 ? cursor[n1] : 0;
        int e0a = e1a - (ok0 ? dg0 : 0);
        int e0b = e1b - (ok1 ? dg1 : 0);
        int cntA = ok0 ? min(dg0, 64) : 0;
        int cntB = ok1 ? min(dg1, 64) : 0;
        float a0 = 0.f, a1 = 0.f, b0 = 0.f, b1 = 0.f;
        gather16x2(z10, adj, e0a, e1a, cntA, e0b, e1b, cntB, lane, a0, a1, b0, b1);
        a0 += __shfl_xor(a0, 16); a1 += __shfl_xor(a1, 16);
        a0 += __shfl_xor(a0, 32); a1 += __shfl_xor(a1, 32);
        b0 += __shfl_xor(b0, 16); b1 += __shfl_xor(b1, 16);
        b0 += __shfl_xor(b0, 32); b1 += __shfl_xor(b1, 32);
        if (ok0 && lane < 16) {
            unsigned int rv = *(const unsigned int*)(r1 + (size_t)n0 * FHID + lane * 2);
            unsigned int w = pk2(fmaxf(a0 + bflo(rv), 0.f), fmaxf(a1 + bfhi(rv), 0.f));
            *(unsigned int*)(out1 + (size_t)n0 * FHID + lane * 2) = w;
        }
        if (ok1 && lane < 16) {
            unsigned int rv = *(const unsigned int*)(r1 + (size_t)n1 * FHID + lane * 2);
            unsigned int w = pk2(fmaxf(b0 + bflo(rv), 0.f), fmaxf(b1 + bfhi(rv), 0.f));
            *(unsigned int*)(out1 + (size_t)n1 * FHID + lane * 2) = w;
        }
    } else {
        int wid = ((blockIdx.x - nbFast) * 256 + t) >> 6;
        int nw = (gridDim.x - nbFast) * 4;
        int u = lane >> 5, o = lane & 31;
        int fcnt = *nflag;
        for (int i = wid; i < fcnt; i += nw) {
            int n = flist[i];
            int d = deg[n];
            // root term: Wr1[d]^T x_n  (split-K across halves u)
            const float* Wr = Wr1 + (size_t)d * (FIN * FHID) + o;
            const float4* xr = (const float4*)(x + (size_t)n * FIN);
            float racc = 0.f;
            for (int c = u * 16; c < u * 16 + 16; ++c) {
                float4 xv = xr[c];
                racc += xv.x * Wr[(c * 4 + 0) * FHID] + xv.y * Wr[(c * 4 + 1) * FHID]
                      + xv.z * Wr[(c * 4 + 2) * FHID] + xv.w * Wr[(c * 4 + 3) * FHID];
            }
            racc += __shfl_xor(racc, 32);
            // neighbor aggregate: h = sum x_j  (feats lane*2, lane*2+1 per lane)
            int e1 = cursor[n];
            int e0 = e1 - d;
            float2 h = make_float2(0.f, 0.f);
            for (int k = e0; k < e1; ++k) {
                int s = adj[k];
                float2 v = *(const float2*)(x + (size_t)s * FIN + lane * 2);
                h.x += v.x; h.y += v.y;
            }
            // transform: W1[d]^T h  (split-K across halves u)
            const float* Wp = W1 + (size_t)d * (FIN * FHID) + o;
            float acc = 0.f;
            for (int f = u * 64; f < u * 64 + 64; ++f) {
                float hf = __shfl((f & 1) ? h.y : h.x, f >> 1);
                acc += hf * Wp[f * FHID];
            }
            acc += __shfl_xor(acc, 32);
            if (lane < 32) {
                float rv = racc + b1[d * FHID + o];
                out1[(size_t)n * FHID + o] = f2bf(fmaxf(acc + rv, 0.f));
            }
        }
    }
}

// ---------- layer2 gather (ALL nodes, 2 per wave): g[n] = sum_{j in N(n)} y_j  (f32) ----------
__global__ __launch_bounds__(256) void k_layer2g(const unsigned short* __restrict__ y,
                                                 const int* __restrict__ deg,
                                                 const int* __restrict__ cursor,
                                                 const int* __restrict__ adj,
                                                 float* __restrict__ g, int N) {
    int t = threadIdx.x;
    int lane = t & 63;
    int n0 = blockIdx.x * 8 + (t >> 6) * 2;
    int n1 = n0 + 1;
    bool ok0 = (n0 < N), ok1 = (n1 < N);
    if (!ok0) return;
    int dg0 = deg[n0];
    int dg1 = ok1 ? deg[n1] : 0;
    int e1a = cursor[n0];
    int e1b = ok1 ? cursor[n1] : 0;
    int e0a = e1a - dg0;
    int e0b = e1b - dg1;
    int cntA = min(dg0, 64);
    int cntB = ok1 ? min(dg1, 64) : 0;
    float a0 = 0.f, a1 = 0.f, b0 = 0.f, b1 = 0.f;
    gather16x2(y, adj, e0a, e1a, cntA, e0b, e1b, cntB, lane, a0, a1, b0, b1);
    a0 += __shfl_xor(a0, 16); a1 += __shfl_xor(a1, 16);
    a0 += __shfl_xor(a0, 32); a1 += __shfl_xor(a1, 32);
    b0 += __shfl_xor(b0, 16); b1 += __shfl_xor(b1, 16);
    b0 += __shfl_xor(b0, 32); b1 += __shfl_xor(b1, 32);
    if (lane < 16) {
        *(float2*)(g + (size_t)n0 * FHID + lane * 2) = make_float2(a0, a1);
        if (ok1) *(float2*)(g + (size_t)n1 * FHID + lane * 2) = make_float2(b0, b1);
    }
}

// ---------- post2 fused: fast blocks MFMA (skip flagged rows); tail blocks exact deg<10 fixup ----------
__global__ __launch_bounds__(256) void k_post2x(const float* __restrict__ g,
                                                const unsigned short* __restrict__ y,
                                                const unsigned short* __restrict__ wcat2,
                                                const float* __restrict__ b2,
                                                const int* __restrict__ deg,
                                                const int* __restrict__ cursor,
                                                const int* __restrict__ adj,
                                                const float* __restrict__ W2full,
                                                const float* __restrict__ Wr2full,
                                                const int* __restrict__ nflag,
                                                const int* __restrict__ flist,
                                                float* __restrict__ out,
                                                int N, int nbFast) {
    int t = threadIdx.x;
    if ((int)blockIdx.x < nbFast) {
        __shared__ __align__(16) unsigned short gt[64 * YPAD];
        __shared__ __align__(16) unsigned short yt[64 * YPAD];
        __shared__ __align__(16) unsigned short wt[128 * YPAD];
        __shared__ unsigned char flg[64];
        int row0 = blockIdx.x * 64;
        {   // stage wcat2 (4096 bf16 = 512 uint4): [128 n][32 k]
            const uint4* src = (const uint4*)wcat2;
#pragma unroll
            for (int i = 0; i < 2; ++i) {
                int idx = i * 256 + t;
                uint4 v = src[idx];
                int nn = idx >> 2;
                int k = (idx & 3) * 8;
                *(uint4*)(wt + nn * YPAD + k) = v;
            }
        }
        if (t < 64) {
            int rn = row0 + t;
            flg[t] = (rn < N) ? (unsigned char)(deg[rn] < MAXDEG) : (unsigned char)1;
        }
        {   // stage g rows (f32 -> bf16) and y rows (bf16)
            int r = t >> 2, c0 = (t & 3) * 8;
            int rn = min(row0 + r, N - 1);
            const float4* gs = (const float4*)(g + (size_t)rn * FHID + c0);
            float4 v0 = gs[0], v1 = gs[1];
            ushort4 p0, p1;
            p0.x = f2bf(v0.x); p0.y = f2bf(v0.y); p0.z = f2bf(v0.z); p0.w = f2bf(v0.w);
            p1.x = f2bf(v1.x); p1.y = f2bf(v1.y); p1.z = f2bf(v1.z); p1.w = f2bf(v1.w);
            *(ushort4*)(gt + r * YPAD + c0) = p0;
            *(ushort4*)(gt + r * YPAD + c0 + 4) = p1;
            uint4 vy = *(const uint4*)(y + (size_t)rn * FHID + c0);
            *(uint4*)(yt + r * YPAD + c0) = vy;
        }
        __syncthreads();
        int w = t >> 6, lane = t & 63;
        int m = lane & 15, quad = lane >> 4;
        short8 ag = *(const short8*)(gt + (w * 16 + m) * YPAD + quad * 8);
        short8 ay = *(const short8*)(yt + (w * 16 + m) * YPAD + quad * 8);
        int rbase = w * 16 + quad * 4;   // block-local row
#pragma unroll
        for (int ct = 0; ct < 4; ++ct) {
            short8 bw = *(const short8*)(wt + (ct * 16 + m) * YPAD + quad * 8);
            short8 br = *(const short8*)(wt + ((64 + ct * 16) + m) * YPAD + quad * 8);
            f32x4 acc = (f32x4){0.f, 0.f, 0.f, 0.f};
            acc = __builtin_amdgcn_mfma_f32_16x16x32_bf16(ag, bw, acc, 0, 0, 0);
            acc = __builtin_amdgcn_mfma_f32_16x16x32_bf16(ay, br, acc, 0, 0, 0);
            int o = ct * 16 + m;
            float bias = b2[MAXDEG * FOUT + o];
#pragma unroll
            for (int rg = 0; rg < 4; ++rg) {
                int rl = rbase + rg;
                int nn = row0 + rl;
                if (nn < N && !flg[rl]) out[(size_t)nn * FOUT + o] = acc[rg] + bias;
            }
        }
    } else {
        int wid = ((blockIdx.x - nbFast) * 256 + t) >> 6;
        int nw = (gridDim.x - nbFast) * 4;
        int lane = t & 63;
        int fcnt = *nflag;
        for (int i = wid; i < fcnt; i += nw) {
            int n = flist[i];
            int d = deg[n];
            float a0 = 0.f, a1 = 0.f;
            if (d > 0) {
                int e1 = cursor[n];
                gather16(y, adj, e1 - d, e1, d, lane, a0, a1);
                a0 += __shfl_xor(a0, 16); a1 += __shfl_xor(a1, 16);
                a0 += __shfl_xor(a0, 32); a1 += __shfl_xor(a1, 32);
            }
            const float* W2p  = W2full  + (size_t)d * (FHID * FOUT) + lane;
            const float* Wr2p = Wr2full + (size_t)d * (FHID * FOUT) + lane;
            unsigned int yw = *(const unsigned int*)(y + (size_t)n * FHID + (lane & 15) * 2);
            float acc = b2[d * FOUT + lane];
#pragma unroll
            for (int q = 0; q < 16; ++q) {
                float g0 = __shfl(a0, q);
                float g1 = __shfl(a1, q);
                unsigned int yq = __shfl(yw, q);
                acc += g0 * W2p[(2 * q) * FOUT] + g1 * W2p[(2 * q + 1) * FOUT]
                     + bflo(yq) * Wr2p[(2 * q) * FOUT] + bfhi(yq) * Wr2p[(2 * q + 1) * FOUT];
            }
            out[(size_t)n * FOUT + lane] = acc;
        }
    }
}

extern "C" void kernel_launch(void* const* d_in, const int* in_sizes, int n_in,
                              void* d_out, int out_size, void* d_ws, size_t ws_size,
                              hipStream_t stream) {
    const float* x   = (const float*)d_in[0];
    const int*   ei  = (const int*)d_in[1];   // int32, [2, E] flat
    const float* W1  = (const float*)d_in[2];
    const float* b1  = (const float*)d_in[3];
    const float* Wr1 = (const float*)d_in[4];
    const float* W2  = (const float*)d_in[5];
    const float* b2  = (const float*)d_in[6];
    const float* Wr2 = (const float*)d_in[7];

    int N = in_sizes[0] / FIN;
    int E = in_sizes[1] / 2;
    int K  = (N + 255) >> BSH;   // dst buckets

    char* ws = (char*)d_ws;
    size_t off = 0;
    auto alloc = [&](size_t bytes) {
        void* ptr = ws + off;
        off += (bytes + 511) / 512 * 512;
        return ptr;
    };
    int* deg              = (int*)alloc((size_t)N * sizeof(int));
    int* cursor           = (int*)alloc((size_t)N * sizeof(int));
    int* bcnt             = (int*)alloc((size_t)(K + 1) * sizeof(int));  // +1: nflag counter
    int* nflag            = bcnt + K;
    int* bstart           = (int*)alloc((size_t)K * sizeof(int));
    int* gcur             = (int*)alloc((size_t)K * sizeof(int));
    int* flist            = (int*)alloc((size_t)N * sizeof(int));
    int* adj              = (int*)alloc((size_t)E * sizeof(int));
    unsigned short* z10   = (unsigned short*)alloc((size_t)N * FHID * 2);
    unsigned short* r1    = (unsigned short*)alloc((size_t)N * FHID * 2);
    unsigned short* out1  = (unsigned short*)alloc((size_t)N * FHID * 2);
    // packed pairs (E*4B) and g (N*FHID*4B) share one region: pairs dead after k_passB2,
    // g first written by k_layer2g which runs later.
    size_t pairsB = (size_t)E * sizeof(unsigned int);
    size_t gB     = (size_t)N * FHID * sizeof(float);
    void* shared_region   = alloc(pairsB > gB ? pairsB : gB);
    float* g              = (float*)shared_region;
    unsigned int* pairs   = (unsigned int*)shared_region;
    unsigned short* wcat1 = (unsigned short*)alloc(64 * 128 * 2);
    unsigned short* wcat2 = (unsigned short*)alloc(128 * 32 * 2);

    float* out = (float*)d_out;

    (void)hipMemsetAsync(bcnt, 0, (size_t)(K + 1) * sizeof(int), stream);

    int nwgA = (E + ACHUNK - 1) / ACHUNK;
    k_bhistp<<<nwgA, 256, 0, stream>>>(ei, E, N, bcnt, W1, Wr1, W2, Wr2, wcat1, wcat2);
    k_scanb<<<1, 1024, 0, stream>>>(bcnt, K, bstart, gcur);
    k_passA<<<nwgA, 256, 0, stream>>>(ei, E, N, gcur, pairs);
    k_passB2<<<K, 256, 0, stream>>>(pairs, bstart, gcur, deg, cursor, adj, nflag, flist, N);

    int nb64 = (N + 63) / 64;     // MFMA kernels: 64 nodes per block
    int nb_pair = (N + 7) / 8;    // gather kernels: 2 nodes per wave, 4 waves per block
    const int FIXB = 512;         // fixup tail blocks (wave-per-flagged-node, grid-stride)

    k_pre1m<<<nb64, 256, 0, stream>>>(x, wcat1, b1, z10, r1, N);
    k_layer1x<<<nb_pair + FIXB, 256, 0, stream>>>(z10, r1, deg, cursor, adj,
                                                  x, W1, b1, Wr1, nflag, flist, out1,
                                                  N, nb_pair);
    k_layer2g<<<nb_pair, 256, 0, stream>>>(out1, deg, cursor, adj, g, N);
    k_post2x<<<nb64 + FIXB, 256, 0, stream>>>(g, out1, wcat2, b2, deg, cursor, adj,
                                              W2, Wr2, nflag, flist, out, N, nb64);
}